// Round 4
// baseline (2399.380 us; speedup 1.0000x reference)
//
#include <hip/hip_runtime.h>

typedef unsigned short u16;
typedef __attribute__((ext_vector_type(8))) short bf16x8;
typedef __attribute__((ext_vector_type(4))) float f32x4;

#define T_TOK 16384
#define DDIM  1024
#define HDIM  4096
#define NEXP  8

// ---------------- ws layout (bytes) ----------------
static constexpr size_t XBF_OFF  = 0;                                   // T*D bf16      = 33.5 MB
static constexpr size_t EW1T_OFF = XBF_OFF  + (size_t)T_TOK*DDIM*2;     // E*H*D bf16    = 67 MB (ew1 transposed: [e][h][d])
static constexpr size_t EW2T_OFF = EW1T_OFF + (size_t)NEXP*HDIM*DDIM*2; // E*D*H bf16    = 67 MB (ew2 transposed: [e][d][h])
static constexpr size_t TOK_OFF  = EW2T_OFF + (size_t)NEXP*DDIM*HDIM*2; // E*T int
static constexpr size_t WT_OFF   = TOK_OFF  + (size_t)NEXP*T_TOK*4;     // E*T float
static constexpr size_t CNT_OFF  = WT_OFF   + (size_t)NEXP*T_TOK*4;     // 8 int (padded 256)
static constexpr size_t BASE_OFF = CNT_OFF  + 256;                      // 8 int (padded 256)
static constexpr size_t BEFF_OFF = BASE_OFF + 256;                      // 1024 float
static constexpr size_t HBUF_OFF = BEFF_OFF + 4096;                     // aliased: gate-h fp32 (64MB) then H bf16
static constexpr size_t HBUF_ROWS = 2*T_TOK + 128;
static constexpr size_t WS_NEED_2048 = HBUF_OFF + HBUF_ROWS*(size_t)2048*2;
static constexpr size_t WS_NEED_4096 = HBUF_OFF + HBUF_ROWS*(size_t)4096*2;

__device__ __forceinline__ u16 f2bf(float f) {
  unsigned u = __float_as_uint(f);
  unsigned r = (u + 0x7FFFu + ((u >> 16) & 1u)) >> 16;   // RNE
  return (u16)r;
}

// async global->LDS, 16B per lane; LDS dest = wave-uniform base + lane*16
#define GL16(gp, lp) __builtin_amdgcn_global_load_lds( \
    (const __attribute__((address_space(1))) void*)(gp), \
    (__attribute__((address_space(3))) void*)(lp), 16, 0, 0)

// ---------------- x -> bf16 ----------------
__global__ __launch_bounds__(256) void k_convert_x(const float* __restrict__ x, u16* __restrict__ xbf, int n4) {
  int i = blockIdx.x * blockDim.x + threadIdx.x;
  int stride = gridDim.x * blockDim.x;
  for (; i < n4; i += stride) {
    float4 v = *(((const float4*)x) + i);
    uint2 pv;
    pv.x = (unsigned)f2bf(v.x) | ((unsigned)f2bf(v.y) << 16);
    pv.y = (unsigned)f2bf(v.z) | ((unsigned)f2bf(v.w) << 16);
    *(uint2*)(xbf + (size_t)i * 4) = pv;
  }
}

// ---------------- effective gate bias: b1 + snr * w1[last row] ----------------
__global__ __launch_bounds__(256) void k_bias_eff(const float* __restrict__ w1, const float* __restrict__ b1,
                                                  const float* __restrict__ snr, float* __restrict__ beff) {
  int j = blockIdx.x * 256 + threadIdx.x;
  if (j < DDIM) beff[j] = b1[j] + snr[0] * w1[(size_t)DDIM * DDIM + j];
}

// ---------------- fp32 [E][R][C] -> bf16 [E][C][R] ----------------
__global__ __launch_bounds__(256) void k_transpose_bf16(const float* __restrict__ in, u16* __restrict__ out,
                                                        int Rr, int Cc) {
  __shared__ u16 tile[64][72];
  const float* inE = in + (size_t)blockIdx.z * Rr * Cc;
  u16* outE = out + (size_t)blockIdx.z * Rr * Cc;
  int r0 = blockIdx.x * 64, c0 = blockIdx.y * 64;
  #pragma unroll
  for (int i = 0; i < 4; i++) {
    int id = threadIdx.x + i * 256;
    int r = id >> 4, cq = id & 15;
    float4 v = *(const float4*)(inE + (size_t)(r0 + r) * Cc + c0 + cq * 4);
    tile[cq*4+0][r] = f2bf(v.x);
    tile[cq*4+1][r] = f2bf(v.y);
    tile[cq*4+2][r] = f2bf(v.z);
    tile[cq*4+3][r] = f2bf(v.w);
  }
  __syncthreads();
  #pragma unroll
  for (int i = 0; i < 2; i++) {
    int id = threadIdx.x + i * 256;
    int c = id >> 3, rq = id & 7;
    *(uint4*)(outE + (size_t)(c0 + c) * Rr + r0 + rq * 8) = *(const uint4*)&tile[c][rq * 8];
  }
}

// ---------------- gate hidden: h = relu(x @ W1[:D,:] + beff), fp32 SGEMM ----------------
// 128x128 tile, 256 threads (16x16), 8x8 per thread, BK=32, single-buffer 2-barrier loop.
__global__ __launch_bounds__(256) void k_gate_h(const float* __restrict__ x, const float* __restrict__ w1,
                                                const float* __restrict__ beff, float* __restrict__ h) {
  __shared__ float As[32][132];   // [k][m]
  __shared__ float B0s[32][68];   // [k][n low half]
  __shared__ float B1s[32][68];   // [k][n high half]
  int m0 = blockIdx.x * 128, n0 = blockIdx.y * 128;
  int tid = threadIdx.x;
  int ty = tid >> 4, tx = tid & 15;
  float acc[8][8] = {};
  for (int k0 = 0; k0 < DDIM; k0 += 32) {
    #pragma unroll
    for (int i = 0; i < 4; i++) {
      int id = tid + i * 256;
      int r = id >> 3, kq = id & 7;
      float4 v = *(const float4*)(x + (size_t)(m0 + r) * DDIM + k0 + kq * 4);
      As[kq*4+0][r] = v.x; As[kq*4+1][r] = v.y; As[kq*4+2][r] = v.z; As[kq*4+3][r] = v.w;
    }
    #pragma unroll
    for (int i = 0; i < 2; i++) {
      int id = tid + i * 256;
      int kk = id >> 4, nq = id & 15;
      float4 v0 = *(const float4*)(w1 + (size_t)(k0 + kk) * DDIM + n0 + nq * 8);
      float4 v1 = *(const float4*)(w1 + (size_t)(k0 + kk) * DDIM + n0 + nq * 8 + 4);
      *(float4*)&B0s[kk][nq*4] = v0;
      *(float4*)&B1s[kk][nq*4] = v1;
    }
    __syncthreads();
    #pragma unroll
    for (int kk = 0; kk < 32; kk++) {
      float a[8], b[8];
      *(float4*)&a[0] = *(const float4*)&As[kk][ty*8];
      *(float4*)&a[4] = *(const float4*)&As[kk][ty*8+4];
      *(float4*)&b[0] = *(const float4*)&B0s[kk][tx*4];
      *(float4*)&b[4] = *(const float4*)&B1s[kk][tx*4];
      #pragma unroll
      for (int mi = 0; mi < 8; mi++)
        #pragma unroll
        for (int ni = 0; ni < 8; ni++)
          acc[mi][ni] = fmaf(a[mi], b[ni], acc[mi][ni]);
    }
    __syncthreads();
  }
  #pragma unroll
  for (int mi = 0; mi < 8; mi++) {
    int row = m0 + ty * 8 + mi;
    int col = n0 + tx * 8;
    float4 o0, o1;
    o0.x = fmaxf(acc[mi][0] + beff[col + 0], 0.f);
    o0.y = fmaxf(acc[mi][1] + beff[col + 1], 0.f);
    o0.z = fmaxf(acc[mi][2] + beff[col + 2], 0.f);
    o0.w = fmaxf(acc[mi][3] + beff[col + 3], 0.f);
    o1.x = fmaxf(acc[mi][4] + beff[col + 4], 0.f);
    o1.y = fmaxf(acc[mi][5] + beff[col + 5], 0.f);
    o1.z = fmaxf(acc[mi][6] + beff[col + 6], 0.f);
    o1.w = fmaxf(acc[mi][7] + beff[col + 7], 0.f);
    *(float4*)(h + (size_t)row * DDIM + col) = o0;
    *(float4*)(h + (size_t)row * DDIM + col + 4) = o1;
  }
}

// ---------------- logits + gumbel softmax + top2 + routing ----------------
__global__ __launch_bounds__(256) void k_gate_logits(const float* __restrict__ h, const float* __restrict__ w2,
    const float* __restrict__ b2, const float* __restrict__ gu, float* __restrict__ scores,
    float* __restrict__ maskp, int* __restrict__ tokl, float* __restrict__ wtl, int* __restrict__ cnts) {
  int wid = threadIdx.x >> 6, lane = threadIdx.x & 63;
  int t = blockIdx.x * 4 + wid;
  const float* hr = h + (size_t)t * DDIM;
  float acc[8] = {0,0,0,0,0,0,0,0};
  for (int kk = 0; kk < DDIM / 64; kk++) {
    int k = kk * 64 + lane;
    float hv = hr[k];
    float4 wa = *(const float4*)(w2 + (size_t)k * 8);
    float4 wb = *(const float4*)(w2 + (size_t)k * 8 + 4);
    acc[0] += hv * wa.x; acc[1] += hv * wa.y; acc[2] += hv * wa.z; acc[3] += hv * wa.w;
    acc[4] += hv * wb.x; acc[5] += hv * wb.y; acc[6] += hv * wb.z; acc[7] += hv * wb.w;
  }
  #pragma unroll
  for (int e = 0; e < 8; e++) {
    #pragma unroll
    for (int off = 32; off > 0; off >>= 1) acc[e] += __shfl_down(acc[e], off);
  }
  if (lane == 0) {
    float sc[8];
    float m = -1e30f;
    #pragma unroll
    for (int e = 0; e < 8; e++) {
      float u = gu[(size_t)t * 8 + e];
      float g = -logf(-logf(u + 1e-9f) + 1e-9f);
      sc[e] = acc[e] + b2[e] + g;          // TAU = 1.0
      m = fmaxf(m, sc[e]);
    }
    float s = 0.f;
    #pragma unroll
    for (int e = 0; e < 8; e++) { sc[e] = expf(sc[e] - m); s += sc[e]; }
    float inv = 1.f / s;
    #pragma unroll
    for (int e = 0; e < 8; e++) { sc[e] *= inv; scores[(size_t)t * 8 + e] = sc[e]; }
    int i1 = 0;
    #pragma unroll
    for (int e = 1; e < 8; e++) if (sc[e] > sc[i1]) i1 = e;        // strict > => lowest index on ties
    int i2 = (i1 == 0) ? 1 : 0;
    #pragma unroll
    for (int e = 0; e < 8; e++) if (e != i1 && sc[e] > sc[i2]) i2 = e;
    #pragma unroll
    for (int e = 0; e < 8; e++) maskp[(size_t)t * 8 + e] = (e == i1 || e == i2) ? 1.f : 0.f;
    int p1 = atomicAdd(&cnts[i1], 1);
    tokl[i1 * T_TOK + p1] = t; wtl[i1 * T_TOK + p1] = sc[i1];
    int p2 = atomicAdd(&cnts[i2], 1);
    tokl[i2 * T_TOK + p2] = t; wtl[i2 * T_TOK + p2] = sc[i2];
  }
}

__global__ void k_scan(const int* __restrict__ cnts, int* __restrict__ basep) {
  if (threadIdx.x == 0 && blockIdx.x == 0) {
    int s = 0;
    for (int e = 0; e < NEXP; e++) { basep[e] = s; s += cnts[e]; }
  }
}

// XCD-chunked token-block remap: bijective on [0,128); active tbs land 2-per-XCD.
__device__ __forceinline__ int tb_swz(int x) {
  return 2 * (x & 7) + ((x >> 3) & 1) + 16 * (x >> 4);
}

// MFMA on one 256x64(A) x 256x64(B) LDS tile. Swizzled: LDS[r][p] = global[r][p^(r&7)].
// 8 waves (2M x 4N); per-wave 128x64 out; acc[8][4].
#define MFMA_STEP256(Abuf, Bbuf)                                                  \
  do {                                                                            \
    _Pragma("unroll")                                                             \
    for (int ks = 0; ks < 2; ks++) {                                              \
      const int chk = ks * 4 + (lane >> 4);                                       \
      bf16x8 af[8], bfr[4];                                                       \
      _Pragma("unroll")                                                           \
      for (int m = 0; m < 8; m++) {                                               \
        int row = wm * 128 + m * 16 + (lane & 15);                                \
        af[m] = *(const bf16x8*)&(Abuf)[row * 64 + ((chk ^ (row & 7)) * 8)];      \
      }                                                                           \
      _Pragma("unroll")                                                           \
      for (int n = 0; n < 4; n++) {                                               \
        int col = wn * 64 + n * 16 + (lane & 15);                                 \
        bfr[n] = *(const bf16x8*)&(Bbuf)[col * 64 + ((chk ^ (col & 7)) * 8)];     \
      }                                                                           \
      _Pragma("unroll")                                                           \
      for (int m = 0; m < 8; m++)                                                 \
        _Pragma("unroll")                                                         \
        for (int n = 0; n < 4; n++)                                               \
          acc[m][n] = __builtin_amdgcn_mfma_f32_16x16x32_bf16(af[m], bfr[n], acc[m][n], 0, 0, 0); \
    }                                                                             \
  } while (0)

// stage one 256x64 A-tile + B-tile; per lane 4+4 gload_lds of 16B.
#define STAGE256(kt)                                        \
  do {                                                      \
    _Pragma("unroll")                                       \
    for (int i = 0; i < 4; i++) {                           \
      GL16(gA[i] + (kt), &As[(i * 64 + wid * 8) * 64]);     \
      GL16(gB[i] + (kt), &Bs[(i * 64 + wid * 8) * 64]);     \
    }                                                       \
  } while (0)

// ---------------- FFN pass 1: H[slot, c0+col] = relu(Xg @ ew1[e] + eb1) ----------------
// 256x256 tile, BK=64, 512 threads, single-buffer 2-barrier loop, gload_lds staging.
__global__ __launch_bounds__(512, 2) void k_ffn1(const u16* __restrict__ xbf, const u16* __restrict__ ew1t,
    const float* __restrict__ eb1, const int* __restrict__ tokl, const int* __restrict__ cnts,
    const int* __restrict__ basep, u16* __restrict__ hbuf, int c0, int HCc) {
  const int e = blockIdx.z;
  const int nt = cnts[e];
  const int r0 = tb_swz(blockIdx.x) * 256;
  if (r0 >= nt) return;
  const int hc0 = blockIdx.y * 256;

  __shared__ u16 As[256 * 64];
  __shared__ u16 Bs[256 * 64];
  __shared__ int toks[256];

  const int tid = threadIdx.x;
  const int wid = tid >> 6, lane = tid & 63;
  if (tid < 256) {
    int row = r0 + tid;
    toks[tid] = tokl[e * T_TOK + (row < nt ? row : nt - 1)];
  }
  __syncthreads();

  const int cXor = ((lane & 7) ^ (lane >> 3)) * 8;
  const u16* gA[4];
  const u16* gB[4];
  #pragma unroll
  for (int i = 0; i < 4; i++) {
    int rr = i * 64 + wid * 8 + (lane >> 3);
    gA[i] = xbf + (size_t)toks[rr] * DDIM + cXor;
    gB[i] = ew1t + ((size_t)e * HDIM + c0 + hc0 + rr) * DDIM + cXor;
  }

  const int wm = wid >> 2, wn = wid & 3;
  f32x4 acc[8][4] = {};

  STAGE256(0);
  for (int kt = 64; kt < DDIM; kt += 64) {
    __syncthreads();
    MFMA_STEP256(As, Bs);
    __syncthreads();
    STAGE256(kt);
  }
  __syncthreads();
  MFMA_STEP256(As, Bs);

  const int g0 = basep[e];
  #pragma unroll
  for (int m = 0; m < 8; m++) {
    int rt0 = wm * 128 + m * 16 + ((lane >> 4) << 2);
    #pragma unroll
    for (int ri = 0; ri < 4; ri++) {
      int rE = r0 + rt0 + ri;
      if (rE < nt) {
        size_t grow = (size_t)(g0 + rE) * HCc;
        #pragma unroll
        for (int n = 0; n < 4; n++) {
          int col = hc0 + wn * 64 + n * 16 + (lane & 15);
          float v = acc[m][n][ri] + eb1[e * HDIM + c0 + col];
          hbuf[grow + col] = f2bf(fmaxf(v, 0.f));
        }
      }
    }
  }
}

// ---------------- FFN pass 2: out[t] += w * (H[slot] @ ew2[e] + eb2) ----------------
__global__ __launch_bounds__(512, 2) void k_ffn2(const u16* __restrict__ hbuf, const u16* __restrict__ ew2t,
    const float* __restrict__ eb2, const int* __restrict__ tokl, const float* __restrict__ wtl,
    const int* __restrict__ cnts, const int* __restrict__ basep, float* __restrict__ out,
    int c0, int HCc) {
  const int e = blockIdx.z;
  const int nt = cnts[e];
  const int r0 = tb_swz(blockIdx.x) * 256;
  if (r0 >= nt) return;
  const int d0 = blockIdx.y * 256;

  __shared__ u16 As[256 * 64];
  __shared__ u16 Bs[256 * 64];
  __shared__ int toks[256];
  __shared__ float wts[256];

  const int tid = threadIdx.x;
  const int wid = tid >> 6, lane = tid & 63;
  const int g0 = basep[e];
  if (tid < 256) {
    int row = r0 + tid;
    int cr = row < nt ? row : nt - 1;
    toks[tid] = tokl[e * T_TOK + cr];
    wts[tid]  = wtl[e * T_TOK + cr];
  }
  __syncthreads();

  const int cXor = ((lane & 7) ^ (lane >> 3)) * 8;
  const u16* gA[4];
  const u16* gB[4];
  #pragma unroll
  for (int i = 0; i < 4; i++) {
    int rr = i * 64 + wid * 8 + (lane >> 3);
    int ra = r0 + rr; if (ra >= nt) ra = nt - 1;          // clamp: no reads past hbuf rows
    gA[i] = hbuf + (size_t)(g0 + ra) * HCc + cXor;
    gB[i] = ew2t + ((size_t)e * DDIM + d0 + rr) * HDIM + c0 + cXor;
  }

  const int wm = wid >> 2, wn = wid & 3;
  f32x4 acc[8][4] = {};

  STAGE256(0);
  for (int kt = 64; kt < HCc; kt += 64) {
    __syncthreads();
    MFMA_STEP256(As, Bs);
    __syncthreads();
    STAGE256(kt);
  }
  __syncthreads();
  MFMA_STEP256(As, Bs);

  #pragma unroll
  for (int m = 0; m < 8; m++) {
    int rt0 = wm * 128 + m * 16 + ((lane >> 4) << 2);
    #pragma unroll
    for (int ri = 0; ri < 4; ri++) {
      int rt = rt0 + ri;
      int rE = r0 + rt;
      if (rE < nt) {
        int t = toks[rt];
        float w = wts[rt];
        #pragma unroll
        for (int n = 0; n < 4; n++) {
          int col = d0 + wn * 64 + n * 16 + (lane & 15);
          float v = acc[m][n][ri];
          if (c0 == 0) v += eb2[e * DDIM + col];
          atomicAdd(&out[(size_t)t * DDIM + col], w * v);
        }
      }
    }
  }
}

// ---------------- launch ----------------
extern "C" void kernel_launch(void* const* d_in, const int* in_sizes, int n_in,
                              void* d_out, int out_size, void* d_ws, size_t ws_size,
                              hipStream_t stream) {
  const float* x   = (const float*)d_in[0];
  const float* snr = (const float*)d_in[1];
  const float* gu  = (const float*)d_in[2];
  const float* gw1 = (const float*)d_in[3];
  const float* gb1 = (const float*)d_in[4];
  const float* gw2 = (const float*)d_in[5];
  const float* gb2 = (const float*)d_in[6];
  const float* ew1 = (const float*)d_in[7];
  const float* eb1 = (const float*)d_in[8];
  const float* ew2 = (const float*)d_in[9];
  const float* eb2 = (const float*)d_in[10];

  if (ws_size < WS_NEED_2048) return;  // outputs stay poisoned -> loud failure signal
  const int HCcur = (ws_size >= WS_NEED_4096) ? 4096 : 2048;   // single-chunk if ws permits

  char* ws = (char*)d_ws;
  u16*   xbf   = (u16*)(ws + XBF_OFF);
  u16*   ew1t  = (u16*)(ws + EW1T_OFF);
  u16*   ew2t  = (u16*)(ws + EW2T_OFF);
  int*   tokl  = (int*)(ws + TOK_OFF);
  float* wtl   = (float*)(ws + WT_OFF);
  int*   cnts  = (int*)(ws + CNT_OFF);
  int*   basep = (int*)(ws + BASE_OFF);
  float* beff  = (float*)(ws + BEFF_OFF);
  float* hgate = (float*)(ws + HBUF_OFF);   // fp32 gate hidden, aliased with hbuf (consumed before FFN1)
  u16*   hbuf  = (u16*)(ws + HBUF_OFF);

  float* out    = (float*)d_out;
  float* scores = out + (size_t)T_TOK * DDIM;
  float* maskp  = scores + (size_t)T_TOK * NEXP;

  hipMemsetAsync(out, 0, (size_t)T_TOK * DDIM * sizeof(float), stream);  // atomics accumulate into this
  hipMemsetAsync(cnts, 0, NEXP * sizeof(int), stream);

  k_convert_x<<<2048, 256, 0, stream>>>(x, xbf, T_TOK * DDIM / 4);
  k_bias_eff<<<(DDIM + 255) / 256, 256, 0, stream>>>(gw1, gb1, snr, beff);
  k_transpose_bf16<<<dim3(DDIM / 64, HDIM / 64, NEXP), 256, 0, stream>>>(ew1, ew1t, DDIM, HDIM);
  k_transpose_bf16<<<dim3(HDIM / 64, DDIM / 64, NEXP), 256, 0, stream>>>(ew2, ew2t, HDIM, DDIM);
  k_gate_h<<<dim3(T_TOK / 128, DDIM / 128), 256, 0, stream>>>(x, gw1, beff, hgate);
  k_gate_logits<<<T_TOK / 4, 256, 0, stream>>>(hgate, gw2, gb2, gu, scores, maskp, tokl, wtl, cnts);
  k_scan<<<1, 64, 0, stream>>>(cnts, basep);

  for (int c = 0; c < HDIM / HCcur; c++) {
    k_ffn1<<<dim3(T_TOK / 128, HCcur / 256, NEXP), 512, 0, stream>>>(xbf, ew1t, eb1, tokl, cnts, basep, hbuf, c * HCcur, HCcur);
    k_ffn2<<<dim3(T_TOK / 128, DDIM / 256, NEXP), 512, 0, stream>>>(hbuf, ew2t, eb2, tokl, wtl, cnts, basep, out, c * HCcur, HCcur);
  }
}

// Round 5
// 1848.737 us; speedup vs baseline: 1.2978x; 1.2978x over previous
//
#include <hip/hip_runtime.h>

typedef unsigned short u16;
typedef __attribute__((ext_vector_type(8))) short bf16x8;
typedef __attribute__((ext_vector_type(4))) float f32x4;

#define T_TOK 16384
#define DDIM  1024
#define HDIM  4096
#define NEXP  8
#define HC    2048   // output-col chunk for ffn1 / K-chunk for ffn2 (2 chunks)

// ---------------- ws layout (bytes) ----------------
static constexpr size_t XBF_OFF  = 0;                                   // T*D bf16      = 33.5 MB
static constexpr size_t EW1T_OFF = XBF_OFF  + (size_t)T_TOK*DDIM*2;     // E*H*D bf16    = 67 MB (ew1^T [e][h][d])
static constexpr size_t EW2T_OFF = EW1T_OFF + (size_t)NEXP*HDIM*DDIM*2; // E*D*H bf16    = 67 MB (ew2^T [e][d][h])
static constexpr size_t TOK_OFF  = EW2T_OFF + (size_t)NEXP*DDIM*HDIM*2; // E*T int
static constexpr size_t WT_OFF   = TOK_OFF  + (size_t)NEXP*T_TOK*4;     // E*T float
static constexpr size_t CNT_OFF  = WT_OFF   + (size_t)NEXP*T_TOK*4;     // 8 int (padded 256)
static constexpr size_t BASE_OFF = CNT_OFF  + 256;                      // 8 int (padded 256)
static constexpr size_t BEFF_OFF = BASE_OFF + 256;                      // 1024 float
static constexpr size_t T2S_OFF  = BEFF_OFF + 4096;                     // T int2  (per-token expert/pos)
static constexpr size_t T2W_OFF  = T2S_OFF  + (size_t)T_TOK*8;          // T float2 (per-token weights)
static constexpr size_t OE_OFF   = T2W_OFF  + (size_t)T_TOK*8;          // slot-major partials f32 [32896][1024] = 134.7 MB (aliases gate-h fp32)
static constexpr size_t OE_ROWS  = 2*T_TOK + 128;
static constexpr size_t HBUF_OFF = OE_OFF + OE_ROWS*(size_t)DDIM*4;     // H bf16 [32896][2048] = 134.7 MB
static constexpr size_t WS_NEEDED = HBUF_OFF + OE_ROWS*(size_t)HC*2;    // 438.57 MB (proven available)

__device__ __forceinline__ u16 f2bf(float f) {
  unsigned u = __float_as_uint(f);
  unsigned r = (u + 0x7FFFu + ((u >> 16) & 1u)) >> 16;   // RNE
  return (u16)r;
}

// async global->LDS, 16B per lane; LDS dest = wave-uniform base + lane*16
#define GL16(gp, lp) __builtin_amdgcn_global_load_lds( \
    (const __attribute__((address_space(1))) void*)(gp), \
    (__attribute__((address_space(3))) void*)(lp), 16, 0, 0)

// ---------------- x -> bf16 ----------------
__global__ __launch_bounds__(256) void k_convert_x(const float* __restrict__ x, u16* __restrict__ xbf, int n4) {
  int i = blockIdx.x * blockDim.x + threadIdx.x;
  int stride = gridDim.x * blockDim.x;
  for (; i < n4; i += stride) {
    float4 v = *(((const float4*)x) + i);
    uint2 pv;
    pv.x = (unsigned)f2bf(v.x) | ((unsigned)f2bf(v.y) << 16);
    pv.y = (unsigned)f2bf(v.z) | ((unsigned)f2bf(v.w) << 16);
    *(uint2*)(xbf + (size_t)i * 4) = pv;
  }
}

// ---------------- effective gate bias: b1 + snr * w1[last row] ----------------
__global__ __launch_bounds__(256) void k_bias_eff(const float* __restrict__ w1, const float* __restrict__ b1,
                                                  const float* __restrict__ snr, float* __restrict__ beff) {
  int j = blockIdx.x * 256 + threadIdx.x;
  if (j < DDIM) beff[j] = b1[j] + snr[0] * w1[(size_t)DDIM * DDIM + j];
}

// ---------------- fp32 [E][R][C] -> bf16 [E][C][R] ----------------
__global__ __launch_bounds__(256) void k_transpose_bf16(const float* __restrict__ in, u16* __restrict__ out,
                                                        int Rr, int Cc) {
  __shared__ u16 tile[64][72];
  const float* inE = in + (size_t)blockIdx.z * Rr * Cc;
  u16* outE = out + (size_t)blockIdx.z * Rr * Cc;
  int r0 = blockIdx.x * 64, c0 = blockIdx.y * 64;
  #pragma unroll
  for (int i = 0; i < 4; i++) {
    int id = threadIdx.x + i * 256;
    int r = id >> 4, cq = id & 15;
    float4 v = *(const float4*)(inE + (size_t)(r0 + r) * Cc + c0 + cq * 4);
    tile[cq*4+0][r] = f2bf(v.x);
    tile[cq*4+1][r] = f2bf(v.y);
    tile[cq*4+2][r] = f2bf(v.z);
    tile[cq*4+3][r] = f2bf(v.w);
  }
  __syncthreads();
  #pragma unroll
  for (int i = 0; i < 2; i++) {
    int id = threadIdx.x + i * 256;
    int c = id >> 3, rq = id & 7;
    *(uint4*)(outE + (size_t)(c0 + c) * Rr + r0 + rq * 8) = *(const uint4*)&tile[c][rq * 8];
  }
}

// ---------------- gate hidden: h = relu(x @ W1[:D,:] + beff), fp32 SGEMM ----------------
// 128x128 tile, 256 threads (16x16), 8x8 per thread, BK=32.
__global__ __launch_bounds__(256) void k_gate_h(const float* __restrict__ x, const float* __restrict__ w1,
                                                const float* __restrict__ beff, float* __restrict__ h) {
  __shared__ float As[32][132];   // [k][m]
  __shared__ float B0s[32][68];   // [k][n low half]
  __shared__ float B1s[32][68];   // [k][n high half]
  int m0 = blockIdx.x * 128, n0 = blockIdx.y * 128;
  int tid = threadIdx.x;
  int ty = tid >> 4, tx = tid & 15;
  float acc[8][8] = {};
  for (int k0 = 0; k0 < DDIM; k0 += 32) {
    #pragma unroll
    for (int i = 0; i < 4; i++) {
      int id = tid + i * 256;
      int r = id >> 3, kq = id & 7;
      float4 v = *(const float4*)(x + (size_t)(m0 + r) * DDIM + k0 + kq * 4);
      As[kq*4+0][r] = v.x; As[kq*4+1][r] = v.y; As[kq*4+2][r] = v.z; As[kq*4+3][r] = v.w;
    }
    #pragma unroll
    for (int i = 0; i < 2; i++) {
      int id = tid + i * 256;
      int kk = id >> 4, nq = id & 15;
      float4 v0 = *(const float4*)(w1 + (size_t)(k0 + kk) * DDIM + n0 + nq * 8);
      float4 v1 = *(const float4*)(w1 + (size_t)(k0 + kk) * DDIM + n0 + nq * 8 + 4);
      *(float4*)&B0s[kk][nq*4] = v0;
      *(float4*)&B1s[kk][nq*4] = v1;
    }
    __syncthreads();
    #pragma unroll
    for (int kk = 0; kk < 32; kk++) {
      float a[8], b[8];
      *(float4*)&a[0] = *(const float4*)&As[kk][ty*8];
      *(float4*)&a[4] = *(const float4*)&As[kk][ty*8+4];
      *(float4*)&b[0] = *(const float4*)&B0s[kk][tx*4];
      *(float4*)&b[4] = *(const float4*)&B1s[kk][tx*4];
      #pragma unroll
      for (int mi = 0; mi < 8; mi++)
        #pragma unroll
        for (int ni = 0; ni < 8; ni++)
          acc[mi][ni] = fmaf(a[mi], b[ni], acc[mi][ni]);
    }
    __syncthreads();
  }
  #pragma unroll
  for (int mi = 0; mi < 8; mi++) {
    int row = m0 + ty * 8 + mi;
    int col = n0 + tx * 8;
    float4 o0, o1;
    o0.x = fmaxf(acc[mi][0] + beff[col + 0], 0.f);
    o0.y = fmaxf(acc[mi][1] + beff[col + 1], 0.f);
    o0.z = fmaxf(acc[mi][2] + beff[col + 2], 0.f);
    o0.w = fmaxf(acc[mi][3] + beff[col + 3], 0.f);
    o1.x = fmaxf(acc[mi][4] + beff[col + 4], 0.f);
    o1.y = fmaxf(acc[mi][5] + beff[col + 5], 0.f);
    o1.z = fmaxf(acc[mi][6] + beff[col + 6], 0.f);
    o1.w = fmaxf(acc[mi][7] + beff[col + 7], 0.f);
    *(float4*)(h + (size_t)row * DDIM + col) = o0;
    *(float4*)(h + (size_t)row * DDIM + col + 4) = o1;
  }
}

// ---------------- logits + gumbel softmax + top2 + routing ----------------
__global__ __launch_bounds__(256) void k_gate_logits(const float* __restrict__ h, const float* __restrict__ w2,
    const float* __restrict__ b2, const float* __restrict__ gu, float* __restrict__ scores,
    float* __restrict__ maskp, int* __restrict__ tokl, int* __restrict__ cnts,
    int2* __restrict__ t2s, float2* __restrict__ t2w) {
  int wid = threadIdx.x >> 6, lane = threadIdx.x & 63;
  int t = blockIdx.x * 4 + wid;
  const float* hr = h + (size_t)t * DDIM;
  float acc[8] = {0,0,0,0,0,0,0,0};
  for (int kk = 0; kk < DDIM / 64; kk++) {
    int k = kk * 64 + lane;
    float hv = hr[k];
    float4 wa = *(const float4*)(w2 + (size_t)k * 8);
    float4 wb = *(const float4*)(w2 + (size_t)k * 8 + 4);
    acc[0] += hv * wa.x; acc[1] += hv * wa.y; acc[2] += hv * wa.z; acc[3] += hv * wa.w;
    acc[4] += hv * wb.x; acc[5] += hv * wb.y; acc[6] += hv * wb.z; acc[7] += hv * wb.w;
  }
  #pragma unroll
  for (int e = 0; e < 8; e++) {
    #pragma unroll
    for (int off = 32; off > 0; off >>= 1) acc[e] += __shfl_down(acc[e], off);
  }
  if (lane == 0) {
    float sc[8];
    float m = -1e30f;
    #pragma unroll
    for (int e = 0; e < 8; e++) {
      float u = gu[(size_t)t * 8 + e];
      float g = -logf(-logf(u + 1e-9f) + 1e-9f);
      sc[e] = acc[e] + b2[e] + g;          // TAU = 1.0
      m = fmaxf(m, sc[e]);
    }
    float s = 0.f;
    #pragma unroll
    for (int e = 0; e < 8; e++) { sc[e] = expf(sc[e] - m); s += sc[e]; }
    float inv = 1.f / s;
    #pragma unroll
    for (int e = 0; e < 8; e++) { sc[e] *= inv; scores[(size_t)t * 8 + e] = sc[e]; }
    int i1 = 0;
    #pragma unroll
    for (int e = 1; e < 8; e++) if (sc[e] > sc[i1]) i1 = e;        // strict > => lowest index on ties
    int i2 = (i1 == 0) ? 1 : 0;
    #pragma unroll
    for (int e = 0; e < 8; e++) if (e != i1 && sc[e] > sc[i2]) i2 = e;
    #pragma unroll
    for (int e = 0; e < 8; e++) maskp[(size_t)t * 8 + e] = (e == i1 || e == i2) ? 1.f : 0.f;
    int p1 = atomicAdd(&cnts[i1], 1);
    tokl[i1 * T_TOK + p1] = t;
    int p2 = atomicAdd(&cnts[i2], 1);
    tokl[i2 * T_TOK + p2] = t;
    t2s[t] = make_int2((i1 << 16) | p1, (i2 << 16) | p2);
    t2w[t] = make_float2(sc[i1], sc[i2]);
  }
}

__global__ void k_scan(const int* __restrict__ cnts, int* __restrict__ basep) {
  if (threadIdx.x == 0 && blockIdx.x == 0) {
    int s = 0;
    for (int e = 0; e < NEXP; e++) { basep[e] = s; s += cnts[e]; }
  }
}

// MFMA compute on one 128x64 LDS tile pair (swizzled: LDS[r][p] = global[r][p^(r&7)])
#define MFMA_STEP(Abuf, Bbuf)                                                     \
  do {                                                                            \
    _Pragma("unroll")                                                             \
    for (int ks = 0; ks < 2; ks++) {                                              \
      const int chk = ks * 4 + (lane >> 4);                                       \
      bf16x8 af[4], bfr[4];                                                       \
      _Pragma("unroll")                                                           \
      for (int m = 0; m < 4; m++) {                                               \
        int row = wr + m * 16 + (lane & 15);                                      \
        af[m] = *(const bf16x8*)&(Abuf)[row * 64 + ((chk ^ (row & 7)) * 8)];      \
      }                                                                           \
      _Pragma("unroll")                                                           \
      for (int n = 0; n < 4; n++) {                                               \
        int col = wc + n * 16 + (lane & 15);                                      \
        bfr[n] = *(const bf16x8*)&(Bbuf)[col * 64 + ((chk ^ (col & 7)) * 8)];     \
      }                                                                           \
      _Pragma("unroll")                                                           \
      for (int m = 0; m < 4; m++)                                                 \
        _Pragma("unroll")                                                         \
        for (int n = 0; n < 4; n++)                                               \
          acc[m][n] = __builtin_amdgcn_mfma_f32_16x16x32_bf16(af[m], bfr[n], acc[m][n], 0, 0, 0); \
    }                                                                             \
  } while (0)

// ---------------- FFN pass 1: H[slot, c0+col] = relu(Xg @ ew1[e] + eb1) ----------------
// m97 structure: 128x128 tile, BK=64, single-buffer global_load_lds, 2 barriers/K-step.
__global__ __launch_bounds__(256) void k_ffn1(const u16* __restrict__ xbf, const u16* __restrict__ ew1t,
    const float* __restrict__ eb1, const int* __restrict__ tokl, const int* __restrict__ cnts,
    const int* __restrict__ basep, u16* __restrict__ hbuf, int c0) {
  const int e = blockIdx.z;
  const int nt = cnts[e];
  const int r0 = blockIdx.x * 128;
  if (r0 >= nt) return;
  const int hc0 = blockIdx.y * 128;

  __shared__ u16 As[8192];
  __shared__ u16 Bs[8192];
  __shared__ int toks[128];

  const int tid = threadIdx.x;
  const int wid = tid >> 6, lane = tid & 63;
  if (tid < 128) {
    int row = r0 + tid;
    toks[tid] = tokl[e * T_TOK + (row < nt ? row : nt - 1)];
  }
  __syncthreads();

  const int cXor = ((lane & 7) ^ (lane >> 3)) * 8;   // pre-swizzled source chunk
  const u16* gA[4];
  const u16* gB[4];
  #pragma unroll
  for (int i = 0; i < 4; i++) {
    int seg = wid * 4 + i;
    int rr = seg * 8 + (lane >> 3);
    gA[i] = xbf + (size_t)toks[rr] * DDIM + cXor;
    gB[i] = ew1t + ((size_t)e * HDIM + c0 + hc0 + rr) * DDIM + cXor;
  }

  const int wr = (wid >> 1) * 64, wc = (wid & 1) * 64;
  f32x4 acc[4][4] = {};

#define STAGE_F1(kt)                                        \
  do {                                                      \
    _Pragma("unroll")                                       \
    for (int i = 0; i < 4; i++) {                           \
      int seg = wid * 4 + i;                                \
      GL16(gA[i] + (kt), &As[seg * 512]);                   \
      GL16(gB[i] + (kt), &Bs[seg * 512]);                   \
    }                                                       \
  } while (0)

  STAGE_F1(0);
  for (int kt = 64; kt < DDIM; kt += 64) {
    __syncthreads();
    MFMA_STEP(As, Bs);
    __syncthreads();
    STAGE_F1(kt);
  }
  __syncthreads();
  MFMA_STEP(As, Bs);

  const int g0 = basep[e];
  #pragma unroll
  for (int m = 0; m < 4; m++) {
    int rt0 = wr + m * 16 + ((lane >> 4) << 2);
    #pragma unroll
    for (int ri = 0; ri < 4; ri++) {
      int rE = r0 + rt0 + ri;
      if (rE < nt) {
        size_t grow = (size_t)(g0 + rE) * HC;
        #pragma unroll
        for (int n = 0; n < 4; n++) {
          int col = hc0 + wc + n * 16 + (lane & 15);
          float v = acc[m][n][ri] + eb1[e * HDIM + c0 + col];
          hbuf[grow + col] = f2bf(fmaxf(v, 0.f));
        }
      }
    }
  }
#undef STAGE_F1
}

// ---------------- FFN pass 2: OE[slot] (+)= H[slot] @ ew2[e] (+ eb2) — NO atomics ----------------
__global__ __launch_bounds__(256) void k_ffn2(const u16* __restrict__ hbuf, const u16* __restrict__ ew2t,
    const float* __restrict__ eb2, const int* __restrict__ cnts, const int* __restrict__ basep,
    float* __restrict__ oe, int c0) {
  const int e = blockIdx.z;
  const int nt = cnts[e];
  const int r0 = blockIdx.x * 128;
  if (r0 >= nt) return;
  const int d0 = blockIdx.y * 128;

  __shared__ u16 As[8192];
  __shared__ u16 Bs[8192];

  const int tid = threadIdx.x;
  const int wid = tid >> 6, lane = tid & 63;
  const int g0 = basep[e];

  const int cXor = ((lane & 7) ^ (lane >> 3)) * 8;
  const u16* gA[4];
  const u16* gB[4];
  #pragma unroll
  for (int i = 0; i < 4; i++) {
    int seg = wid * 4 + i;
    int rr = seg * 8 + (lane >> 3);
    int ra = r0 + rr; if (ra >= nt) ra = nt - 1;   // clamp (results discarded)
    gA[i] = hbuf + (size_t)(g0 + ra) * HC + cXor;
    gB[i] = ew2t + ((size_t)e * DDIM + d0 + rr) * HDIM + c0 + cXor;
  }

  const int wr = (wid >> 1) * 64, wc = (wid & 1) * 64;
  f32x4 acc[4][4] = {};

#define STAGE_F2(kt)                                        \
  do {                                                      \
    _Pragma("unroll")                                       \
    for (int i = 0; i < 4; i++) {                           \
      int seg = wid * 4 + i;                                \
      GL16(gA[i] + (kt), &As[seg * 512]);                   \
      GL16(gB[i] + (kt), &Bs[seg * 512]);                   \
    }                                                       \
  } while (0)

  STAGE_F2(0);
  for (int kt = 64; kt < HC; kt += 64) {
    __syncthreads();
    MFMA_STEP(As, Bs);
    __syncthreads();
    STAGE_F2(kt);
  }
  __syncthreads();
  MFMA_STEP(As, Bs);

  #pragma unroll
  for (int m = 0; m < 4; m++) {
    int rt0 = wr + m * 16 + ((lane >> 4) << 2);
    #pragma unroll
    for (int ri = 0; ri < 4; ri++) {
      int rE = r0 + rt0 + ri;
      if (rE < nt) {
        float* orow = oe + (size_t)(g0 + rE) * DDIM;
        #pragma unroll
        for (int n = 0; n < 4; n++) {
          int col = d0 + wc + n * 16 + (lane & 15);
          float v = acc[m][n][ri];
          if (c0 == 0) orow[col] = v + eb2[e * DDIM + col];   // first K-chunk: init (+bias)
          else         orow[col] += v;                        // second K-chunk: private RMW
        }
      }
    }
  }
#undef STAGE_F2
}

// ---------------- combine: out[t] = wA*OE[slotA] + wB*OE[slotB] ----------------
__global__ __launch_bounds__(256) void k_combine(const float* __restrict__ oe,
    const int2* __restrict__ t2s, const float2* __restrict__ t2w, const int* __restrict__ basep,
    float* __restrict__ out) {
  int wid = threadIdx.x >> 6, lane = threadIdx.x & 63;
  int t = blockIdx.x * 4 + wid;
  int2 s = t2s[t];
  float2 w = t2w[t];
  const float4* pa = (const float4*)(oe + (size_t)(basep[s.x >> 16] + (s.x & 0xFFFF)) * DDIM);
  const float4* pb = (const float4*)(oe + (size_t)(basep[s.y >> 16] + (s.y & 0xFFFF)) * DDIM);
  float4* po = (float4*)(out + (size_t)t * DDIM);
  #pragma unroll
  for (int k = 0; k < 4; k++) {
    int i = k * 64 + lane;
    float4 a = pa[i], b = pb[i];
    float4 o;
    o.x = w.x * a.x + w.y * b.x;
    o.y = w.x * a.y + w.y * b.y;
    o.z = w.x * a.z + w.y * b.z;
    o.w = w.x * a.w + w.y * b.w;
    po[i] = o;
  }
}

// ---------------- launch ----------------
extern "C" void kernel_launch(void* const* d_in, const int* in_sizes, int n_in,
                              void* d_out, int out_size, void* d_ws, size_t ws_size,
                              hipStream_t stream) {
  const float* x   = (const float*)d_in[0];
  const float* snr = (const float*)d_in[1];
  const float* gu  = (const float*)d_in[2];
  const float* gw1 = (const float*)d_in[3];
  const float* gb1 = (const float*)d_in[4];
  const float* gw2 = (const float*)d_in[5];
  const float* gb2 = (const float*)d_in[6];
  const float* ew1 = (const float*)d_in[7];
  const float* eb1 = (const float*)d_in[8];
  const float* ew2 = (const float*)d_in[9];
  const float* eb2 = (const float*)d_in[10];

  if (ws_size < WS_NEEDED) return;  // outputs stay poisoned -> loud failure signal

  char* ws = (char*)d_ws;
  u16*    xbf   = (u16*)(ws + XBF_OFF);
  u16*    ew1t  = (u16*)(ws + EW1T_OFF);
  u16*    ew2t  = (u16*)(ws + EW2T_OFF);
  int*    tokl  = (int*)(ws + TOK_OFF);
  int*    cnts  = (int*)(ws + CNT_OFF);
  int*    basep = (int*)(ws + BASE_OFF);
  float*  beff  = (float*)(ws + BEFF_OFF);
  int2*   t2s   = (int2*)(ws + T2S_OFF);
  float2* t2w   = (float2*)(ws + T2W_OFF);
  float*  oe    = (float*)(ws + OE_OFF);
  float*  hgate = (float*)(ws + OE_OFF);    // fp32 gate hidden aliases OE (disjoint lifetimes)
  u16*    hbuf  = (u16*)(ws + HBUF_OFF);

  float* out    = (float*)d_out;
  float* scores = out + (size_t)T_TOK * DDIM;
  float* maskp  = scores + (size_t)T_TOK * NEXP;

  hipMemsetAsync(cnts, 0, NEXP * sizeof(int), stream);

  k_convert_x<<<2048, 256, 0, stream>>>(x, xbf, T_TOK * DDIM / 4);
  k_bias_eff<<<(DDIM + 255) / 256, 256, 0, stream>>>(gw1, gb1, snr, beff);
  k_transpose_bf16<<<dim3(DDIM / 64, HDIM / 64, NEXP), 256, 0, stream>>>(ew1, ew1t, DDIM, HDIM);
  k_transpose_bf16<<<dim3(HDIM / 64, DDIM / 64, NEXP), 256, 0, stream>>>(ew2, ew2t, HDIM, DDIM);
  k_gate_h<<<dim3(T_TOK / 128, DDIM / 128), 256, 0, stream>>>(x, gw1, beff, hgate);
  k_gate_logits<<<T_TOK / 4, 256, 0, stream>>>(hgate, gw2, gb2, gu, scores, maskp, tokl, cnts, t2s, t2w);
  k_scan<<<1, 64, 0, stream>>>(cnts, basep);

  for (int c = 0; c < HDIM / HC; c++) {
    k_ffn1<<<dim3(T_TOK / 128, HC / 128, NEXP), 256, 0, stream>>>(xbf, ew1t, eb1, tokl, cnts, basep, hbuf, c * HC);
    k_ffn2<<<dim3(T_TOK / 128, DDIM / 128, NEXP), 256, 0, stream>>>(hbuf, ew2t, eb2, cnts, basep, oe, c * HC);
  }
  k_combine<<<T_TOK / 4, 256, 0, stream>>>(oe, t2s, t2w, basep, out);
}

// Round 6
// 1599.290 us; speedup vs baseline: 1.5003x; 1.1560x over previous
//
#include <hip/hip_runtime.h>

typedef unsigned short u16;
typedef __attribute__((ext_vector_type(8))) short bf16x8;
typedef __attribute__((ext_vector_type(4))) float f32x4;

#define T_TOK 16384
#define DDIM  1024
#define HDIM  4096
#define NEXP  8
#define HC    2048   // output-col chunk for ffn1 / K-chunk for ffn2 (2 chunks)

// ---------------- ws layout (bytes) ----------------
static constexpr size_t XBF_OFF  = 0;                                   // T*D bf16      = 33.5 MB (x hi)
static constexpr size_t EW1T_OFF = XBF_OFF  + (size_t)T_TOK*DDIM*2;     // E*H*D bf16    = 67 MB (ew1^T [e][h][d])
static constexpr size_t EW2T_OFF = EW1T_OFF + (size_t)NEXP*HDIM*DDIM*2; // E*D*H bf16    = 67 MB (ew2^T [e][d][h])
static constexpr size_t TOK_OFF  = EW2T_OFF + (size_t)NEXP*DDIM*HDIM*2; // E*T int
static constexpr size_t WT_OFF   = TOK_OFF  + (size_t)NEXP*T_TOK*4;     // (spare)
static constexpr size_t CNT_OFF  = WT_OFF   + (size_t)NEXP*T_TOK*4;     // 8 int (padded 256)
static constexpr size_t BASE_OFF = CNT_OFF  + 256;                      // 8 int (padded 256)
static constexpr size_t BEFF_OFF = BASE_OFF + 256;                      // 1024 float
static constexpr size_t T2S_OFF  = BEFF_OFF + 4096;                     // T int2  (per-token expert/pos)
static constexpr size_t T2W_OFF  = T2S_OFF  + (size_t)T_TOK*8;          // T float2 (per-token weights)
static constexpr size_t OE_OFF   = T2W_OFF  + (size_t)T_TOK*8;          // slot-major partials f32 [32896][1024] = 134.7 MB (aliases gate-h fp32)
static constexpr size_t OE_ROWS  = 2*T_TOK + 128;
static constexpr size_t HBUF_OFF = OE_OFF + OE_ROWS*(size_t)DDIM*4;     // H bf16 [32896][2048] = 134.7 MB
static constexpr size_t WS_NEEDED = HBUF_OFF + OE_ROWS*(size_t)HC*2;    // 438.57 MB (proven available)
// gate-phase aliases inside HBUF region (dead before k_ffn1 writes hbuf):
static constexpr size_t XLO_OFF  = HBUF_OFF;                            // T*D bf16 = 33.5 MB (x lo)
static constexpr size_t W1HT_OFF = XLO_OFF + (size_t)T_TOK*DDIM*2;      // D*D bf16 = 2 MB (W1 hi ^T)
static constexpr size_t W1LT_OFF = W1HT_OFF + (size_t)DDIM*DDIM*2;      // D*D bf16 = 2 MB (W1 lo ^T)

__device__ __forceinline__ u16 f2bf(float f) {
  unsigned u = __float_as_uint(f);
  unsigned r = (u + 0x7FFFu + ((u >> 16) & 1u)) >> 16;   // RNE
  return (u16)r;
}
__device__ __forceinline__ float bf2f(u16 b) { return __uint_as_float(((unsigned)b) << 16); }

// async global->LDS, 16B per lane; LDS dest = wave-uniform base + lane*16
#define GL16(gp, lp) __builtin_amdgcn_global_load_lds( \
    (const __attribute__((address_space(1))) void*)(gp), \
    (__attribute__((address_space(3))) void*)(lp), 16, 0, 0)

// ---------------- x -> bf16 hi + lo ----------------
__global__ __launch_bounds__(256) void k_convert_x2(const float* __restrict__ x, u16* __restrict__ xh,
                                                    u16* __restrict__ xl, int n4) {
  int i = blockIdx.x * blockDim.x + threadIdx.x;
  int stride = gridDim.x * blockDim.x;
  for (; i < n4; i += stride) {
    float4 v = *(((const float4*)x) + i);
    u16 h0 = f2bf(v.x), h1 = f2bf(v.y), h2 = f2bf(v.z), h3 = f2bf(v.w);
    u16 l0 = f2bf(v.x - bf2f(h0)), l1 = f2bf(v.y - bf2f(h1));
    u16 l2 = f2bf(v.z - bf2f(h2)), l3 = f2bf(v.w - bf2f(h3));
    uint2 ph, pl;
    ph.x = (unsigned)h0 | ((unsigned)h1 << 16);
    ph.y = (unsigned)h2 | ((unsigned)h3 << 16);
    pl.x = (unsigned)l0 | ((unsigned)l1 << 16);
    pl.y = (unsigned)l2 | ((unsigned)l3 << 16);
    *(uint2*)(xh + (size_t)i * 4) = ph;
    *(uint2*)(xl + (size_t)i * 4) = pl;
  }
}

// ---------------- effective gate bias: b1 + snr * w1[last row] ----------------
__global__ __launch_bounds__(256) void k_bias_eff(const float* __restrict__ w1, const float* __restrict__ b1,
                                                  const float* __restrict__ snr, float* __restrict__ beff) {
  int j = blockIdx.x * 256 + threadIdx.x;
  if (j < DDIM) beff[j] = b1[j] + snr[0] * w1[(size_t)DDIM * DDIM + j];
}

// ---------------- fp32 [E][R][C] -> bf16 [E][C][R] ----------------
__global__ __launch_bounds__(256) void k_transpose_bf16(const float* __restrict__ in, u16* __restrict__ out,
                                                        int Rr, int Cc) {
  __shared__ u16 tile[64][72];
  const float* inE = in + (size_t)blockIdx.z * Rr * Cc;
  u16* outE = out + (size_t)blockIdx.z * Rr * Cc;
  int r0 = blockIdx.x * 64, c0 = blockIdx.y * 64;
  #pragma unroll
  for (int i = 0; i < 4; i++) {
    int id = threadIdx.x + i * 256;
    int r = id >> 4, cq = id & 15;
    float4 v = *(const float4*)(inE + (size_t)(r0 + r) * Cc + c0 + cq * 4);
    tile[cq*4+0][r] = f2bf(v.x);
    tile[cq*4+1][r] = f2bf(v.y);
    tile[cq*4+2][r] = f2bf(v.z);
    tile[cq*4+3][r] = f2bf(v.w);
  }
  __syncthreads();
  #pragma unroll
  for (int i = 0; i < 2; i++) {
    int id = threadIdx.x + i * 256;
    int c = id >> 3, rq = id & 7;
    *(uint4*)(outE + (size_t)(c0 + c) * Rr + r0 + rq * 8) = *(const uint4*)&tile[c][rq * 8];
  }
}

// ---------------- W1 (fp32 [k][n], first 1024 rows) -> hi/lo bf16 ^T [n][k] ----------------
__global__ __launch_bounds__(256) void k_transpose_w1split(const float* __restrict__ w1,
                                                           u16* __restrict__ hT, u16* __restrict__ lT) {
  __shared__ u16 th[64][72];
  __shared__ u16 tl[64][72];
  int r0 = blockIdx.x * 64, c0 = blockIdx.y * 64;
  #pragma unroll
  for (int i = 0; i < 4; i++) {
    int id = threadIdx.x + i * 256;
    int r = id >> 4, cq = id & 15;
    float4 v = *(const float4*)(w1 + (size_t)(r0 + r) * DDIM + c0 + cq * 4);
    u16 h0 = f2bf(v.x), h1 = f2bf(v.y), h2 = f2bf(v.z), h3 = f2bf(v.w);
    th[cq*4+0][r] = h0; tl[cq*4+0][r] = f2bf(v.x - bf2f(h0));
    th[cq*4+1][r] = h1; tl[cq*4+1][r] = f2bf(v.y - bf2f(h1));
    th[cq*4+2][r] = h2; tl[cq*4+2][r] = f2bf(v.z - bf2f(h2));
    th[cq*4+3][r] = h3; tl[cq*4+3][r] = f2bf(v.w - bf2f(h3));
  }
  __syncthreads();
  #pragma unroll
  for (int i = 0; i < 2; i++) {
    int id = threadIdx.x + i * 256;
    int c = id >> 3, rq = id & 7;
    *(uint4*)(hT + (size_t)(c0 + c) * DDIM + r0 + rq * 8) = *(const uint4*)&th[c][rq * 8];
    *(uint4*)(lT + (size_t)(c0 + c) * DDIM + r0 + rq * 8) = *(const uint4*)&tl[c][rq * 8];
  }
}

// MFMA compute on one 128x64 LDS tile pair (swizzled: LDS[r][p] = global[r][p^(r&7)])
#define MFMA_STEP(Abuf, Bbuf)                                                     \
  do {                                                                            \
    _Pragma("unroll")                                                             \
    for (int ks = 0; ks < 2; ks++) {                                              \
      const int chk = ks * 4 + (lane >> 4);                                       \
      bf16x8 af[4], bfr[4];                                                       \
      _Pragma("unroll")                                                           \
      for (int m = 0; m < 4; m++) {                                               \
        int row = wr + m * 16 + (lane & 15);                                      \
        af[m] = *(const bf16x8*)&(Abuf)[row * 64 + ((chk ^ (row & 7)) * 8)];      \
      }                                                                           \
      _Pragma("unroll")                                                           \
      for (int n = 0; n < 4; n++) {                                               \
        int col = wc + n * 16 + (lane & 15);                                      \
        bfr[n] = *(const bf16x8*)&(Bbuf)[col * 64 + ((chk ^ (col & 7)) * 8)];     \
      }                                                                           \
      _Pragma("unroll")                                                           \
      for (int m = 0; m < 4; m++)                                                 \
        _Pragma("unroll")                                                         \
        for (int n = 0; n < 4; n++)                                               \
          acc[m][n] = __builtin_amdgcn_mfma_f32_16x16x32_bf16(af[m], bfr[n], acc[m][n], 0, 0, 0); \
    }                                                                             \
  } while (0)

// ---------------- gate hidden: h = relu(xh@Wh + xh@Wl + xl@Wh + beff), 3-pass bf16-split MFMA ----------------
// m97 128x128 structure; 48 K-steps = 3 passes x 16. h error ~1e-5 << min top-2/3 gap.
__global__ __launch_bounds__(256) void k_gate_h_mfma(const u16* __restrict__ xh, const u16* __restrict__ xl,
    const u16* __restrict__ w1hT, const u16* __restrict__ w1lT,
    const float* __restrict__ beff, float* __restrict__ h) {
  const int m0 = blockIdx.x * 128, n0 = blockIdx.y * 128;
  __shared__ u16 As[8192];
  __shared__ u16 Bs[8192];
  const int tid = threadIdx.x;
  const int wid = tid >> 6, lane = tid & 63;

  const int cXor = ((lane & 7) ^ (lane >> 3)) * 8;
  size_t aoff[4], boff[4];
  #pragma unroll
  for (int i = 0; i < 4; i++) {
    int seg = wid * 4 + i;
    int rr = seg * 8 + (lane >> 3);
    aoff[i] = (size_t)(m0 + rr) * DDIM + cXor;
    boff[i] = (size_t)(n0 + rr) * DDIM + cXor;
  }
  const u16* Ab[3] = {xh, xh, xl};
  const u16* Bb[3] = {w1hT, w1lT, w1hT};

  const int wr = (wid >> 1) * 64, wc = (wid & 1) * 64;
  f32x4 acc[4][4] = {};

#define STAGE_G(s)                                          \
  do {                                                      \
    const u16* Abase = Ab[(s) >> 4];                        \
    const u16* Bbase = Bb[(s) >> 4];                        \
    const int kt = ((s) & 15) * 64;                         \
    _Pragma("unroll")                                       \
    for (int i = 0; i < 4; i++) {                           \
      int seg = wid * 4 + i;                                \
      GL16(Abase + aoff[i] + kt, &As[seg * 512]);           \
      GL16(Bbase + boff[i] + kt, &Bs[seg * 512]);           \
    }                                                       \
  } while (0)

  STAGE_G(0);
  for (int s = 1; s < 48; s++) {
    __syncthreads();
    MFMA_STEP(As, Bs);
    __syncthreads();
    STAGE_G(s);
  }
  __syncthreads();
  MFMA_STEP(As, Bs);

  #pragma unroll
  for (int m = 0; m < 4; m++) {
    int rt0 = wr + m * 16 + ((lane >> 4) << 2);
    #pragma unroll
    for (int ri = 0; ri < 4; ri++) {
      int row = m0 + rt0 + ri;
      #pragma unroll
      for (int n = 0; n < 4; n++) {
        int col = n0 + wc + n * 16 + (lane & 15);
        h[(size_t)row * DDIM + col] = fmaxf(acc[m][n][ri] + beff[col], 0.f);
      }
    }
  }
#undef STAGE_G
}

// ---------------- logits + gumbel softmax + top2 + routing ----------------
__global__ __launch_bounds__(256) void k_gate_logits(const float* __restrict__ h, const float* __restrict__ w2,
    const float* __restrict__ b2, const float* __restrict__ gu, float* __restrict__ scores,
    float* __restrict__ maskp, int* __restrict__ tokl, int* __restrict__ cnts,
    int2* __restrict__ t2s, float2* __restrict__ t2w) {
  int wid = threadIdx.x >> 6, lane = threadIdx.x & 63;
  int t = blockIdx.x * 4 + wid;
  const float* hr = h + (size_t)t * DDIM;
  float acc[8] = {0,0,0,0,0,0,0,0};
  for (int kk = 0; kk < DDIM / 64; kk++) {
    int k = kk * 64 + lane;
    float hv = hr[k];
    float4 wa = *(const float4*)(w2 + (size_t)k * 8);
    float4 wb = *(const float4*)(w2 + (size_t)k * 8 + 4);
    acc[0] += hv * wa.x; acc[1] += hv * wa.y; acc[2] += hv * wa.z; acc[3] += hv * wa.w;
    acc[4] += hv * wb.x; acc[5] += hv * wb.y; acc[6] += hv * wb.z; acc[7] += hv * wb.w;
  }
  #pragma unroll
  for (int e = 0; e < 8; e++) {
    #pragma unroll
    for (int off = 32; off > 0; off >>= 1) acc[e] += __shfl_down(acc[e], off);
  }
  if (lane == 0) {
    float sc[8];
    float m = -1e30f;
    #pragma unroll
    for (int e = 0; e < 8; e++) {
      float u = gu[(size_t)t * 8 + e];
      float g = -logf(-logf(u + 1e-9f) + 1e-9f);
      sc[e] = acc[e] + b2[e] + g;          // TAU = 1.0
      m = fmaxf(m, sc[e]);
    }
    float s = 0.f;
    #pragma unroll
    for (int e = 0; e < 8; e++) { sc[e] = expf(sc[e] - m); s += sc[e]; }
    float inv = 1.f / s;
    #pragma unroll
    for (int e = 0; e < 8; e++) { sc[e] *= inv; scores[(size_t)t * 8 + e] = sc[e]; }
    int i1 = 0;
    #pragma unroll
    for (int e = 1; e < 8; e++) if (sc[e] > sc[i1]) i1 = e;        // strict > => lowest index on ties
    int i2 = (i1 == 0) ? 1 : 0;
    #pragma unroll
    for (int e = 0; e < 8; e++) if (e != i1 && sc[e] > sc[i2]) i2 = e;
    #pragma unroll
    for (int e = 0; e < 8; e++) maskp[(size_t)t * 8 + e] = (e == i1 || e == i2) ? 1.f : 0.f;
    int p1 = atomicAdd(&cnts[i1], 1);
    tokl[i1 * T_TOK + p1] = t;
    int p2 = atomicAdd(&cnts[i2], 1);
    tokl[i2 * T_TOK + p2] = t;
    t2s[t] = make_int2((i1 << 16) | p1, (i2 << 16) | p2);
    t2w[t] = make_float2(sc[i1], sc[i2]);
  }
}

__global__ void k_scan(const int* __restrict__ cnts, int* __restrict__ basep) {
  if (threadIdx.x == 0 && blockIdx.x == 0) {
    int s = 0;
    for (int e = 0; e < NEXP; e++) { basep[e] = s; s += cnts[e]; }
  }
}

// ---------------- FFN pass 1: H[slot, c0+col] = relu(Xg @ ew1[e] + eb1) ----------------
// m97 structure: 128x128 tile, BK=64, single-buffer global_load_lds, 2 barriers/K-step.
__global__ __launch_bounds__(256) void k_ffn1(const u16* __restrict__ xbf, const u16* __restrict__ ew1t,
    const float* __restrict__ eb1, const int* __restrict__ tokl, const int* __restrict__ cnts,
    const int* __restrict__ basep, u16* __restrict__ hbuf, int c0) {
  const int e = blockIdx.z;
  const int nt = cnts[e];
  const int r0 = blockIdx.x * 128;
  if (r0 >= nt) return;
  const int hc0 = blockIdx.y * 128;

  __shared__ u16 As[8192];
  __shared__ u16 Bs[8192];
  __shared__ int toks[128];

  const int tid = threadIdx.x;
  const int wid = tid >> 6, lane = tid & 63;
  if (tid < 128) {
    int row = r0 + tid;
    toks[tid] = tokl[e * T_TOK + (row < nt ? row : nt - 1)];
  }
  __syncthreads();

  const int cXor = ((lane & 7) ^ (lane >> 3)) * 8;   // pre-swizzled source chunk
  const u16* gA[4];
  const u16* gB[4];
  #pragma unroll
  for (int i = 0; i < 4; i++) {
    int seg = wid * 4 + i;
    int rr = seg * 8 + (lane >> 3);
    gA[i] = xbf + (size_t)toks[rr] * DDIM + cXor;
    gB[i] = ew1t + ((size_t)e * HDIM + c0 + hc0 + rr) * DDIM + cXor;
  }

  const int wr = (wid >> 1) * 64, wc = (wid & 1) * 64;
  f32x4 acc[4][4] = {};

#define STAGE_F1(kt)                                        \
  do {                                                      \
    _Pragma("unroll")                                       \
    for (int i = 0; i < 4; i++) {                           \
      int seg = wid * 4 + i;                                \
      GL16(gA[i] + (kt), &As[seg * 512]);                   \
      GL16(gB[i] + (kt), &Bs[seg * 512]);                   \
    }                                                       \
  } while (0)

  STAGE_F1(0);
  for (int kt = 64; kt < DDIM; kt += 64) {
    __syncthreads();
    MFMA_STEP(As, Bs);
    __syncthreads();
    STAGE_F1(kt);
  }
  __syncthreads();
  MFMA_STEP(As, Bs);

  const int g0 = basep[e];
  #pragma unroll
  for (int m = 0; m < 4; m++) {
    int rt0 = wr + m * 16 + ((lane >> 4) << 2);
    #pragma unroll
    for (int ri = 0; ri < 4; ri++) {
      int rE = r0 + rt0 + ri;
      if (rE < nt) {
        size_t grow = (size_t)(g0 + rE) * HC;
        #pragma unroll
        for (int n = 0; n < 4; n++) {
          int col = hc0 + wc + n * 16 + (lane & 15);
          float v = acc[m][n][ri] + eb1[e * HDIM + c0 + col];
          hbuf[grow + col] = f2bf(fmaxf(v, 0.f));
        }
      }
    }
  }
#undef STAGE_F1
}

// ---------------- FFN pass 2: OE[slot] (+)= H[slot] @ ew2[e] (+ eb2) — NO atomics ----------------
__global__ __launch_bounds__(256) void k_ffn2(const u16* __restrict__ hbuf, const u16* __restrict__ ew2t,
    const float* __restrict__ eb2, const int* __restrict__ cnts, const int* __restrict__ basep,
    float* __restrict__ oe, int c0) {
  const int e = blockIdx.z;
  const int nt = cnts[e];
  const int r0 = blockIdx.x * 128;
  if (r0 >= nt) return;
  const int d0 = blockIdx.y * 128;

  __shared__ u16 As[8192];
  __shared__ u16 Bs[8192];

  const int tid = threadIdx.x;
  const int wid = tid >> 6, lane = tid & 63;
  const int g0 = basep[e];

  const int cXor = ((lane & 7) ^ (lane >> 3)) * 8;
  const u16* gA[4];
  const u16* gB[4];
  #pragma unroll
  for (int i = 0; i < 4; i++) {
    int seg = wid * 4 + i;
    int rr = seg * 8 + (lane >> 3);
    int ra = r0 + rr; if (ra >= nt) ra = nt - 1;   // clamp (results discarded)
    gA[i] = hbuf + (size_t)(g0 + ra) * HC + cXor;
    gB[i] = ew2t + ((size_t)e * DDIM + d0 + rr) * HDIM + c0 + cXor;
  }

  const int wr = (wid >> 1) * 64, wc = (wid & 1) * 64;
  f32x4 acc[4][4] = {};

#define STAGE_F2(kt)                                        \
  do {                                                      \
    _Pragma("unroll")                                       \
    for (int i = 0; i < 4; i++) {                           \
      int seg = wid * 4 + i;                                \
      GL16(gA[i] + (kt), &As[seg * 512]);                   \
      GL16(gB[i] + (kt), &Bs[seg * 512]);                   \
    }                                                       \
  } while (0)

  STAGE_F2(0);
  for (int kt = 64; kt < HC; kt += 64) {
    __syncthreads();
    MFMA_STEP(As, Bs);
    __syncthreads();
    STAGE_F2(kt);
  }
  __syncthreads();
  MFMA_STEP(As, Bs);

  #pragma unroll
  for (int m = 0; m < 4; m++) {
    int rt0 = wr + m * 16 + ((lane >> 4) << 2);
    #pragma unroll
    for (int ri = 0; ri < 4; ri++) {
      int rE = r0 + rt0 + ri;
      if (rE < nt) {
        float* orow = oe + (size_t)(g0 + rE) * DDIM;
        #pragma unroll
        for (int n = 0; n < 4; n++) {
          int col = d0 + wc + n * 16 + (lane & 15);
          float v = acc[m][n][ri];
          if (c0 == 0) orow[col] = v + eb2[e * DDIM + col];   // first K-chunk: init (+bias)
          else         orow[col] += v;                        // second K-chunk: private RMW
        }
      }
    }
  }
#undef STAGE_F2
}

// ---------------- combine: out[t] = wA*OE[slotA] + wB*OE[slotB] ----------------
__global__ __launch_bounds__(256) void k_combine(const float* __restrict__ oe,
    const int2* __restrict__ t2s, const float2* __restrict__ t2w, const int* __restrict__ basep,
    float* __restrict__ out) {
  int wid = threadIdx.x >> 6, lane = threadIdx.x & 63;
  int t = blockIdx.x * 4 + wid;
  int2 s = t2s[t];
  float2 w = t2w[t];
  const float4* pa = (const float4*)(oe + (size_t)(basep[s.x >> 16] + (s.x & 0xFFFF)) * DDIM);
  const float4* pb = (const float4*)(oe + (size_t)(basep[s.y >> 16] + (s.y & 0xFFFF)) * DDIM);
  float4* po = (float4*)(out + (size_t)t * DDIM);
  #pragma unroll
  for (int k = 0; k < 4; k++) {
    int i = k * 64 + lane;
    float4 a = pa[i], b = pb[i];
    float4 o;
    o.x = w.x * a.x + w.y * b.x;
    o.y = w.x * a.y + w.y * b.y;
    o.z = w.x * a.z + w.y * b.z;
    o.w = w.x * a.w + w.y * b.w;
    po[i] = o;
  }
}

// ---------------- launch ----------------
extern "C" void kernel_launch(void* const* d_in, const int* in_sizes, int n_in,
                              void* d_out, int out_size, void* d_ws, size_t ws_size,
                              hipStream_t stream) {
  const float* x   = (const float*)d_in[0];
  const float* snr = (const float*)d_in[1];
  const float* gu  = (const float*)d_in[2];
  const float* gw1 = (const float*)d_in[3];
  const float* gb1 = (const float*)d_in[4];
  const float* gw2 = (const float*)d_in[5];
  const float* gb2 = (const float*)d_in[6];
  const float* ew1 = (const float*)d_in[7];
  const float* eb1 = (const float*)d_in[8];
  const float* ew2 = (const float*)d_in[9];
  const float* eb2 = (const float*)d_in[10];

  if (ws_size < WS_NEEDED) return;  // outputs stay poisoned -> loud failure signal

  char* ws = (char*)d_ws;
  u16*    xbf   = (u16*)(ws + XBF_OFF);
  u16*    ew1t  = (u16*)(ws + EW1T_OFF);
  u16*    ew2t  = (u16*)(ws + EW2T_OFF);
  int*    tokl  = (int*)(ws + TOK_OFF);
  int*    cnts  = (int*)(ws + CNT_OFF);
  int*    basep = (int*)(ws + BASE_OFF);
  float*  beff  = (float*)(ws + BEFF_OFF);
  int2*   t2s   = (int2*)(ws + T2S_OFF);
  float2* t2w   = (float2*)(ws + T2W_OFF);
  float*  oe    = (float*)(ws + OE_OFF);
  float*  hgate = (float*)(ws + OE_OFF);    // fp32 gate hidden aliases OE (disjoint lifetimes)
  u16*    hbuf  = (u16*)(ws + HBUF_OFF);
  u16*    xlo   = (u16*)(ws + XLO_OFF);     // aliases hbuf region (dead before ffn1)
  u16*    w1hT  = (u16*)(ws + W1HT_OFF);
  u16*    w1lT  = (u16*)(ws + W1LT_OFF);

  float* out    = (float*)d_out;
  float* scores = out + (size_t)T_TOK * DDIM;
  float* maskp  = scores + (size_t)T_TOK * NEXP;

  hipMemsetAsync(cnts, 0, NEXP * sizeof(int), stream);

  k_convert_x2<<<2048, 256, 0, stream>>>(x, xbf, xlo, T_TOK * DDIM / 4);
  k_bias_eff<<<(DDIM + 255) / 256, 256, 0, stream>>>(gw1, gb1, snr, beff);
  k_transpose_w1split<<<dim3(DDIM / 64, DDIM / 64), 256, 0, stream>>>(gw1, w1hT, w1lT);
  k_transpose_bf16<<<dim3(DDIM / 64, HDIM / 64, NEXP), 256, 0, stream>>>(ew1, ew1t, DDIM, HDIM);
  k_transpose_bf16<<<dim3(HDIM / 64, DDIM / 64, NEXP), 256, 0, stream>>>(ew2, ew2t, HDIM, DDIM);
  k_gate_h_mfma<<<dim3(T_TOK / 128, DDIM / 128), 256, 0, stream>>>(xbf, xlo, w1hT, w1lT, beff, hgate);
  k_gate_logits<<<T_TOK / 4, 256, 0, stream>>>(hgate, gw2, gb2, gu, scores, maskp, tokl, cnts, t2s, t2w);
  k_scan<<<1, 64, 0, stream>>>(cnts, basep);

  for (int c = 0; c < HDIM / HC; c++) {
    k_ffn1<<<dim3(T_TOK / 128, HC / 128, NEXP), 256, 0, stream>>>(xbf, ew1t, eb1, tokl, cnts, basep, hbuf, c * HC);
    k_ffn2<<<dim3(T_TOK / 128, DDIM / 128, NEXP), 256, 0, stream>>>(hbuf, ew2t, eb2, cnts, basep, oe, c * HC);
  }
  k_combine<<<T_TOK / 4, 256, 0, stream>>>(oe, t2s, t2w, basep, out);
}

// Round 7
// 1247.265 us; speedup vs baseline: 1.9237x; 1.2822x over previous
//
#include <hip/hip_runtime.h>

typedef unsigned short u16;
typedef __attribute__((ext_vector_type(8))) short bf16x8;
typedef __attribute__((ext_vector_type(4))) float f32x4;

#define T_TOK 16384
#define DDIM  1024
#define HDIM  4096
#define NEXP  8
#define HC    2048   // output-col chunk for ffn1 / K-chunk for ffn2 (2 chunks)

// ---------------- ws layout (bytes) ----------------
static constexpr size_t XBF_OFF  = 0;                                   // T*D bf16      = 33.5 MB (x hi)
static constexpr size_t EW1T_OFF = XBF_OFF  + (size_t)T_TOK*DDIM*2;     // E*H*D bf16    = 67 MB (ew1^T [e][h][d])
static constexpr size_t EW2T_OFF = EW1T_OFF + (size_t)NEXP*HDIM*DDIM*2; // E*D*H bf16    = 67 MB (ew2^T [e][d][h])
static constexpr size_t TOK_OFF  = EW2T_OFF + (size_t)NEXP*DDIM*HDIM*2; // E*T int (expert token lists)
static constexpr size_t PICK_OFF = TOK_OFF  + (size_t)NEXP*T_TOK*4;     // T int (i1 | i2<<8)
static constexpr size_t CNT_OFF  = PICK_OFF + (size_t)NEXP*T_TOK*4;     // 8 int (padded 256)
static constexpr size_t BASE_OFF = CNT_OFF  + 256;                      // 8 int (padded 256)
static constexpr size_t BEFF_OFF = BASE_OFF + 256;                      // 1024 float
static constexpr size_t T2S_OFF  = BEFF_OFF + 4096;                     // T int2 (slotA, slotB: (e<<16)|rank)
static constexpr size_t T2W_OFF  = T2S_OFF  + (size_t)T_TOK*8;          // T float2 (per-token weights)
static constexpr size_t OE_OFF   = T2W_OFF  + (size_t)T_TOK*8;          // slot-major partials f32 [32896][1024] = 134.7 MB (aliases gate-h fp32)
static constexpr size_t OE_ROWS  = 2*T_TOK + 128;
static constexpr size_t HBUF_OFF = OE_OFF + OE_ROWS*(size_t)DDIM*4;     // H bf16 [32896][2048] = 134.7 MB
static constexpr size_t WS_NEEDED = HBUF_OFF + OE_ROWS*(size_t)HC*2;    // 438.57 MB (proven available)
// gate-phase aliases inside HBUF region (dead before k_ffn1 writes hbuf):
static constexpr size_t XLO_OFF  = HBUF_OFF;                            // T*D bf16 = 33.5 MB (x lo)
static constexpr size_t W1HT_OFF = XLO_OFF + (size_t)T_TOK*DDIM*2;      // D*D bf16 = 2 MB (W1 hi ^T)
static constexpr size_t W1LT_OFF = W1HT_OFF + (size_t)DDIM*DDIM*2;      // D*D bf16 = 2 MB (W1 lo ^T)

__device__ __forceinline__ u16 f2bf(float f) {
  unsigned u = __float_as_uint(f);
  unsigned r = (u + 0x7FFFu + ((u >> 16) & 1u)) >> 16;   // RNE
  return (u16)r;
}
__device__ __forceinline__ float bf2f(u16 b) { return __uint_as_float(((unsigned)b) << 16); }

// async global->LDS, 16B per lane; LDS dest = wave-uniform base + lane*16
#define GL16(gp, lp) __builtin_amdgcn_global_load_lds( \
    (const __attribute__((address_space(1))) void*)(gp), \
    (__attribute__((address_space(3))) void*)(lp), 16, 0, 0)

// ---------------- x -> bf16 hi + lo ----------------
__global__ __launch_bounds__(256) void k_convert_x2(const float* __restrict__ x, u16* __restrict__ xh,
                                                    u16* __restrict__ xl, int n4) {
  int i = blockIdx.x * blockDim.x + threadIdx.x;
  int stride = gridDim.x * blockDim.x;
  for (; i < n4; i += stride) {
    float4 v = *(((const float4*)x) + i);
    u16 h0 = f2bf(v.x), h1 = f2bf(v.y), h2 = f2bf(v.z), h3 = f2bf(v.w);
    u16 l0 = f2bf(v.x - bf2f(h0)), l1 = f2bf(v.y - bf2f(h1));
    u16 l2 = f2bf(v.z - bf2f(h2)), l3 = f2bf(v.w - bf2f(h3));
    uint2 ph, pl;
    ph.x = (unsigned)h0 | ((unsigned)h1 << 16);
    ph.y = (unsigned)h2 | ((unsigned)h3 << 16);
    pl.x = (unsigned)l0 | ((unsigned)l1 << 16);
    pl.y = (unsigned)l2 | ((unsigned)l3 << 16);
    *(uint2*)(xh + (size_t)i * 4) = ph;
    *(uint2*)(xl + (size_t)i * 4) = pl;
  }
}

// ---------------- effective gate bias: b1 + snr * w1[last row] ----------------
__global__ __launch_bounds__(256) void k_bias_eff(const float* __restrict__ w1, const float* __restrict__ b1,
                                                  const float* __restrict__ snr, float* __restrict__ beff) {
  int j = blockIdx.x * 256 + threadIdx.x;
  if (j < DDIM) beff[j] = b1[j] + snr[0] * w1[(size_t)DDIM * DDIM + j];
}

// ---------------- fp32 [E][R][C] -> bf16 [E][C][R] ----------------
__global__ __launch_bounds__(256) void k_transpose_bf16(const float* __restrict__ in, u16* __restrict__ out,
                                                        int Rr, int Cc) {
  __shared__ u16 tile[64][72];
  const float* inE = in + (size_t)blockIdx.z * Rr * Cc;
  u16* outE = out + (size_t)blockIdx.z * Rr * Cc;
  int r0 = blockIdx.x * 64, c0 = blockIdx.y * 64;
  #pragma unroll
  for (int i = 0; i < 4; i++) {
    int id = threadIdx.x + i * 256;
    int r = id >> 4, cq = id & 15;
    float4 v = *(const float4*)(inE + (size_t)(r0 + r) * Cc + c0 + cq * 4);
    tile[cq*4+0][r] = f2bf(v.x);
    tile[cq*4+1][r] = f2bf(v.y);
    tile[cq*4+2][r] = f2bf(v.z);
    tile[cq*4+3][r] = f2bf(v.w);
  }
  __syncthreads();
  #pragma unroll
  for (int i = 0; i < 2; i++) {
    int id = threadIdx.x + i * 256;
    int c = id >> 3, rq = id & 7;
    *(uint4*)(outE + (size_t)(c0 + c) * Rr + r0 + rq * 8) = *(const uint4*)&tile[c][rq * 8];
  }
}

// ---------------- W1 (fp32 [k][n], first 1024 rows) -> hi/lo bf16 ^T [n][k] ----------------
__global__ __launch_bounds__(256) void k_transpose_w1split(const float* __restrict__ w1,
                                                           u16* __restrict__ hT, u16* __restrict__ lT) {
  __shared__ u16 th[64][72];
  __shared__ u16 tl[64][72];
  int r0 = blockIdx.x * 64, c0 = blockIdx.y * 64;
  #pragma unroll
  for (int i = 0; i < 4; i++) {
    int id = threadIdx.x + i * 256;
    int r = id >> 4, cq = id & 15;
    float4 v = *(const float4*)(w1 + (size_t)(r0 + r) * DDIM + c0 + cq * 4);
    u16 h0 = f2bf(v.x), h1 = f2bf(v.y), h2 = f2bf(v.z), h3 = f2bf(v.w);
    th[cq*4+0][r] = h0; tl[cq*4+0][r] = f2bf(v.x - bf2f(h0));
    th[cq*4+1][r] = h1; tl[cq*4+1][r] = f2bf(v.y - bf2f(h1));
    th[cq*4+2][r] = h2; tl[cq*4+2][r] = f2bf(v.z - bf2f(h2));
    th[cq*4+3][r] = h3; tl[cq*4+3][r] = f2bf(v.w - bf2f(h3));
  }
  __syncthreads();
  #pragma unroll
  for (int i = 0; i < 2; i++) {
    int id = threadIdx.x + i * 256;
    int c = id >> 3, rq = id & 7;
    *(uint4*)(hT + (size_t)(c0 + c) * DDIM + r0 + rq * 8) = *(const uint4*)&th[c][rq * 8];
    *(uint4*)(lT + (size_t)(c0 + c) * DDIM + r0 + rq * 8) = *(const uint4*)&tl[c][rq * 8];
  }
}

// MFMA compute on one 128x64 LDS tile pair (swizzled: LDS[r][p] = global[r][p^(r&7)])
#define MFMA_STEP(Abuf, Bbuf)                                                     \
  do {                                                                            \
    _Pragma("unroll")                                                             \
    for (int ks = 0; ks < 2; ks++) {                                              \
      const int chk = ks * 4 + (lane >> 4);                                       \
      bf16x8 af[4], bfr[4];                                                       \
      _Pragma("unroll")                                                           \
      for (int m = 0; m < 4; m++) {                                               \
        int row = wr + m * 16 + (lane & 15);                                      \
        af[m] = *(const bf16x8*)&(Abuf)[row * 64 + ((chk ^ (row & 7)) * 8)];      \
      }                                                                           \
      _Pragma("unroll")                                                           \
      for (int n = 0; n < 4; n++) {                                               \
        int col = wc + n * 16 + (lane & 15);                                      \
        bfr[n] = *(const bf16x8*)&(Bbuf)[col * 64 + ((chk ^ (col & 7)) * 8)];     \
      }                                                                           \
      _Pragma("unroll")                                                           \
      for (int m = 0; m < 4; m++)                                                 \
        _Pragma("unroll")                                                         \
        for (int n = 0; n < 4; n++)                                               \
          acc[m][n] = __builtin_amdgcn_mfma_f32_16x16x32_bf16(af[m], bfr[n], acc[m][n], 0, 0, 0); \
    }                                                                             \
  } while (0)

// ---------------- gate hidden: h = relu(xh@Wh + xh@Wl + xl@Wh + beff), 3-pass bf16-split MFMA ----------------
__global__ __launch_bounds__(256) void k_gate_h_mfma(const u16* __restrict__ xh, const u16* __restrict__ xl,
    const u16* __restrict__ w1hT, const u16* __restrict__ w1lT,
    const float* __restrict__ beff, float* __restrict__ h) {
  const int m0 = blockIdx.x * 128, n0 = blockIdx.y * 128;
  __shared__ u16 As[8192];
  __shared__ u16 Bs[8192];
  const int tid = threadIdx.x;
  const int wid = tid >> 6, lane = tid & 63;

  const int cXor = ((lane & 7) ^ (lane >> 3)) * 8;
  size_t aoff[4], boff[4];
  #pragma unroll
  for (int i = 0; i < 4; i++) {
    int seg = wid * 4 + i;
    int rr = seg * 8 + (lane >> 3);
    aoff[i] = (size_t)(m0 + rr) * DDIM + cXor;
    boff[i] = (size_t)(n0 + rr) * DDIM + cXor;
  }
  const u16* Ab[3] = {xh, xh, xl};
  const u16* Bb[3] = {w1hT, w1lT, w1hT};

  const int wr = (wid >> 1) * 64, wc = (wid & 1) * 64;
  f32x4 acc[4][4] = {};

#define STAGE_G(s)                                          \
  do {                                                      \
    const u16* Abase = Ab[(s) >> 4];                        \
    const u16* Bbase = Bb[(s) >> 4];                        \
    const int kt = ((s) & 15) * 64;                         \
    _Pragma("unroll")                                       \
    for (int i = 0; i < 4; i++) {                           \
      int seg = wid * 4 + i;                                \
      GL16(Abase + aoff[i] + kt, &As[seg * 512]);           \
      GL16(Bbase + boff[i] + kt, &Bs[seg * 512]);           \
    }                                                       \
  } while (0)

  STAGE_G(0);
  for (int s = 1; s < 48; s++) {
    __syncthreads();
    MFMA_STEP(As, Bs);
    __syncthreads();
    STAGE_G(s);
  }
  __syncthreads();
  MFMA_STEP(As, Bs);

  #pragma unroll
  for (int m = 0; m < 4; m++) {
    int rt0 = wr + m * 16 + ((lane >> 4) << 2);
    #pragma unroll
    for (int ri = 0; ri < 4; ri++) {
      int row = m0 + rt0 + ri;
      #pragma unroll
      for (int n = 0; n < 4; n++) {
        int col = n0 + wc + n * 16 + (lane & 15);
        h[(size_t)row * DDIM + col] = fmaxf(acc[m][n][ri] + beff[col], 0.f);
      }
    }
  }
#undef STAGE_G
}

// ---------------- Phase A: logits + gumbel softmax + top2 picks (NO atomics) ----------------
__global__ __launch_bounds__(256) void k_gate_logits(const float* __restrict__ h, const float* __restrict__ w2,
    const float* __restrict__ b2, const float* __restrict__ gu, float* __restrict__ scores,
    float* __restrict__ maskp, int* __restrict__ pick, float2* __restrict__ t2w) {
  int wid = threadIdx.x >> 6, lane = threadIdx.x & 63;
  int t = blockIdx.x * 4 + wid;
  const float* hr = h + (size_t)t * DDIM;
  float acc[8] = {0,0,0,0,0,0,0,0};
  for (int kk = 0; kk < DDIM / 64; kk++) {
    int k = kk * 64 + lane;
    float hv = hr[k];
    float4 wa = *(const float4*)(w2 + (size_t)k * 8);
    float4 wb = *(const float4*)(w2 + (size_t)k * 8 + 4);
    acc[0] += hv * wa.x; acc[1] += hv * wa.y; acc[2] += hv * wa.z; acc[3] += hv * wa.w;
    acc[4] += hv * wb.x; acc[5] += hv * wb.y; acc[6] += hv * wb.z; acc[7] += hv * wb.w;
  }
  #pragma unroll
  for (int e = 0; e < 8; e++) {
    #pragma unroll
    for (int off = 32; off > 0; off >>= 1) acc[e] += __shfl_down(acc[e], off);
  }
  if (lane == 0) {
    float sc[8];
    float m = -1e30f;
    #pragma unroll
    for (int e = 0; e < 8; e++) {
      float u = gu[(size_t)t * 8 + e];
      float g = -logf(-logf(u + 1e-9f) + 1e-9f);
      sc[e] = acc[e] + b2[e] + g;          // TAU = 1.0
      m = fmaxf(m, sc[e]);
    }
    float s = 0.f;
    #pragma unroll
    for (int e = 0; e < 8; e++) { sc[e] = expf(sc[e] - m); s += sc[e]; }
    float inv = 1.f / s;
    #pragma unroll
    for (int e = 0; e < 8; e++) { sc[e] *= inv; scores[(size_t)t * 8 + e] = sc[e]; }
    int i1 = 0;
    #pragma unroll
    for (int e = 1; e < 8; e++) if (sc[e] > sc[i1]) i1 = e;        // strict > => lowest index on ties
    int i2 = (i1 == 0) ? 1 : 0;
    #pragma unroll
    for (int e = 0; e < 8; e++) if (e != i1 && sc[e] > sc[i2]) i2 = e;
    #pragma unroll
    for (int e = 0; e < 8; e++) maskp[(size_t)t * 8 + e] = (e == i1 || e == i2) ? 1.f : 0.f;
    pick[t] = i1 | (i2 << 8);
    t2w[t] = make_float2(sc[i1], sc[i2]);
  }
}

// ---------------- Phase B: deterministic routing via prefix scan (8 blocks, one per expert) ----------------
// Builds sorted-by-token expert lists + per-token slot ids. No contended atomics.
__global__ __launch_bounds__(1024) void k_route(const int* __restrict__ pick,
    int* __restrict__ tokl, int* __restrict__ cnts, int* __restrict__ t2si) {
  const int e = blockIdx.x;
  const int tid = threadIdx.x;
  const int lane = tid & 63, w = tid >> 6;   // 16 waves
  __shared__ int wsum[16];
  __shared__ int wbase[16];

  const int t0 = tid * 16;
  int flags = 0, fsel = 0;
  #pragma unroll
  for (int j = 0; j < 16; j++) {
    int p = pick[t0 + j];
    int i1 = p & 0xFF, i2 = (p >> 8) & 0xFF;
    if (i1 == e) { flags |= 1 << j; fsel |= 1 << j; }
    else if (i2 == e) { flags |= 1 << j; }
  }
  int c = __popc(flags);
  // wave inclusive scan of c
  int incl = c;
  #pragma unroll
  for (int off = 1; off < 64; off <<= 1) {
    int vv = __shfl_up(incl, off);
    if (lane >= off) incl += vv;
  }
  int waveTotal = __shfl(incl, 63);
  int myExcl = incl - c;
  if (lane == 63) wsum[w] = waveTotal;
  __syncthreads();
  if (tid == 0) {
    int s = 0;
    #pragma unroll
    for (int i = 0; i < 16; i++) { wbase[i] = s; s += wsum[i]; }
    cnts[e] = s;
  }
  __syncthreads();
  int rank = wbase[w] + myExcl;
  #pragma unroll
  for (int j = 0; j < 16; j++) {
    if (flags & (1 << j)) {
      int t = t0 + j;
      tokl[e * T_TOK + rank] = t;
      t2si[2 * t + (((fsel >> j) & 1) ? 0 : 1)] = (e << 16) | rank;
      rank++;
    }
  }
}

__global__ void k_scan(const int* __restrict__ cnts, int* __restrict__ basep) {
  if (threadIdx.x == 0 && blockIdx.x == 0) {
    int s = 0;
    for (int e = 0; e < NEXP; e++) { basep[e] = s; s += cnts[e]; }
  }
}

// ---------------- FFN pass 1: H[slot, c0+col] = relu(Xg @ ew1[e] + eb1) ----------------
// m97 structure: 128x128 tile, BK=64, single-buffer global_load_lds, 2 barriers/K-step.
__global__ __launch_bounds__(256) void k_ffn1(const u16* __restrict__ xbf, const u16* __restrict__ ew1t,
    const float* __restrict__ eb1, const int* __restrict__ tokl, const int* __restrict__ cnts,
    const int* __restrict__ basep, u16* __restrict__ hbuf, int c0) {
  const int e = blockIdx.z;
  const int nt = cnts[e];
  const int r0 = blockIdx.x * 128;
  if (r0 >= nt) return;
  const int hc0 = blockIdx.y * 128;

  __shared__ u16 As[8192];
  __shared__ u16 Bs[8192];
  __shared__ int toks[128];

  const int tid = threadIdx.x;
  const int wid = tid >> 6, lane = tid & 63;
  if (tid < 128) {
    int row = r0 + tid;
    toks[tid] = tokl[e * T_TOK + (row < nt ? row : nt - 1)];
  }
  __syncthreads();

  const int cXor = ((lane & 7) ^ (lane >> 3)) * 8;   // pre-swizzled source chunk
  const u16* gA[4];
  const u16* gB[4];
  #pragma unroll
  for (int i = 0; i < 4; i++) {
    int seg = wid * 4 + i;
    int rr = seg * 8 + (lane >> 3);
    gA[i] = xbf + (size_t)toks[rr] * DDIM + cXor;
    gB[i] = ew1t + ((size_t)e * HDIM + c0 + hc0 + rr) * DDIM + cXor;
  }

  const int wr = (wid >> 1) * 64, wc = (wid & 1) * 64;
  f32x4 acc[4][4] = {};

#define STAGE_F1(kt)                                        \
  do {                                                      \
    _Pragma("unroll")                                       \
    for (int i = 0; i < 4; i++) {                           \
      int seg = wid * 4 + i;                                \
      GL16(gA[i] + (kt), &As[seg * 512]);                   \
      GL16(gB[i] + (kt), &Bs[seg * 512]);                   \
    }                                                       \
  } while (0)

  STAGE_F1(0);
  for (int kt = 64; kt < DDIM; kt += 64) {
    __syncthreads();
    MFMA_STEP(As, Bs);
    __syncthreads();
    STAGE_F1(kt);
  }
  __syncthreads();
  MFMA_STEP(As, Bs);

  const int g0 = basep[e];
  #pragma unroll
  for (int m = 0; m < 4; m++) {
    int rt0 = wr + m * 16 + ((lane >> 4) << 2);
    #pragma unroll
    for (int ri = 0; ri < 4; ri++) {
      int rE = r0 + rt0 + ri;
      if (rE < nt) {
        size_t grow = (size_t)(g0 + rE) * HC;
        #pragma unroll
        for (int n = 0; n < 4; n++) {
          int col = hc0 + wc + n * 16 + (lane & 15);
          float v = acc[m][n][ri] + eb1[e * HDIM + c0 + col];
          hbuf[grow + col] = f2bf(fmaxf(v, 0.f));
        }
      }
    }
  }
#undef STAGE_F1
}

// ---------------- FFN pass 2: OE[slot] (+)= H[slot] @ ew2[e] (+ eb2) — NO atomics ----------------
__global__ __launch_bounds__(256) void k_ffn2(const u16* __restrict__ hbuf, const u16* __restrict__ ew2t,
    const float* __restrict__ eb2, const int* __restrict__ cnts, const int* __restrict__ basep,
    float* __restrict__ oe, int c0) {
  const int e = blockIdx.z;
  const int nt = cnts[e];
  const int r0 = blockIdx.x * 128;
  if (r0 >= nt) return;
  const int d0 = blockIdx.y * 128;

  __shared__ u16 As[8192];
  __shared__ u16 Bs[8192];

  const int tid = threadIdx.x;
  const int wid = tid >> 6, lane = tid & 63;
  const int g0 = basep[e];

  const int cXor = ((lane & 7) ^ (lane >> 3)) * 8;
  const u16* gA[4];
  const u16* gB[4];
  #pragma unroll
  for (int i = 0; i < 4; i++) {
    int seg = wid * 4 + i;
    int rr = seg * 8 + (lane >> 3);
    int ra = r0 + rr; if (ra >= nt) ra = nt - 1;   // clamp (results discarded)
    gA[i] = hbuf + (size_t)(g0 + ra) * HC + cXor;
    gB[i] = ew2t + ((size_t)e * DDIM + d0 + rr) * HDIM + c0 + cXor;
  }

  const int wr = (wid >> 1) * 64, wc = (wid & 1) * 64;
  f32x4 acc[4][4] = {};

#define STAGE_F2(kt)                                        \
  do {                                                      \
    _Pragma("unroll")                                       \
    for (int i = 0; i < 4; i++) {                           \
      int seg = wid * 4 + i;                                \
      GL16(gA[i] + (kt), &As[seg * 512]);                   \
      GL16(gB[i] + (kt), &Bs[seg * 512]);                   \
    }                                                       \
  } while (0)

  STAGE_F2(0);
  for (int kt = 64; kt < HC; kt += 64) {
    __syncthreads();
    MFMA_STEP(As, Bs);
    __syncthreads();
    STAGE_F2(kt);
  }
  __syncthreads();
  MFMA_STEP(As, Bs);

  #pragma unroll
  for (int m = 0; m < 4; m++) {
    int rt0 = wr + m * 16 + ((lane >> 4) << 2);
    #pragma unroll
    for (int ri = 0; ri < 4; ri++) {
      int rE = r0 + rt0 + ri;
      if (rE < nt) {
        float* orow = oe + (size_t)(g0 + rE) * DDIM;
        #pragma unroll
        for (int n = 0; n < 4; n++) {
          int col = d0 + wc + n * 16 + (lane & 15);
          float v = acc[m][n][ri];
          if (c0 == 0) orow[col] = v + eb2[e * DDIM + col];   // first K-chunk: init (+bias)
          else         orow[col] += v;                        // second K-chunk: private RMW
        }
      }
    }
  }
#undef STAGE_F2
}

// ---------------- combine: out[t] = wA*OE[slotA] + wB*OE[slotB] ----------------
__global__ __launch_bounds__(256) void k_combine(const float* __restrict__ oe,
    const int2* __restrict__ t2s, const float2* __restrict__ t2w, const int* __restrict__ basep,
    float* __restrict__ out) {
  int wid = threadIdx.x >> 6, lane = threadIdx.x & 63;
  int t = blockIdx.x * 4 + wid;
  int2 s = t2s[t];
  float2 w = t2w[t];
  const float4* pa = (const float4*)(oe + (size_t)(basep[s.x >> 16] + (s.x & 0xFFFF)) * DDIM);
  const float4* pb = (const float4*)(oe + (size_t)(basep[s.y >> 16] + (s.y & 0xFFFF)) * DDIM);
  float4* po = (float4*)(out + (size_t)t * DDIM);
  #pragma unroll
  for (int k = 0; k < 4; k++) {
    int i = k * 64 + lane;
    float4 a = pa[i], b = pb[i];
    float4 o;
    o.x = w.x * a.x + w.y * b.x;
    o.y = w.x * a.y + w.y * b.y;
    o.z = w.x * a.z + w.y * b.z;
    o.w = w.x * a.w + w.y * b.w;
    po[i] = o;
  }
}

// ---------------- launch ----------------
extern "C" void kernel_launch(void* const* d_in, const int* in_sizes, int n_in,
                              void* d_out, int out_size, void* d_ws, size_t ws_size,
                              hipStream_t stream) {
  const float* x   = (const float*)d_in[0];
  const float* snr = (const float*)d_in[1];
  const float* gu  = (const float*)d_in[2];
  const float* gw1 = (const float*)d_in[3];
  const float* gb1 = (const float*)d_in[4];
  const float* gw2 = (const float*)d_in[5];
  const float* gb2 = (const float*)d_in[6];
  const float* ew1 = (const float*)d_in[7];
  const float* eb1 = (const float*)d_in[8];
  const float* ew2 = (const float*)d_in[9];
  const float* eb2 = (const float*)d_in[10];

  if (ws_size < WS_NEEDED) return;  // outputs stay poisoned -> loud failure signal

  char* ws = (char*)d_ws;
  u16*    xbf   = (u16*)(ws + XBF_OFF);
  u16*    ew1t  = (u16*)(ws + EW1T_OFF);
  u16*    ew2t  = (u16*)(ws + EW2T_OFF);
  int*    tokl  = (int*)(ws + TOK_OFF);
  int*    pick  = (int*)(ws + PICK_OFF);
  int*    cnts  = (int*)(ws + CNT_OFF);
  int*    basep = (int*)(ws + BASE_OFF);
  float*  beff  = (float*)(ws + BEFF_OFF);
  int*    t2si  = (int*)(ws + T2S_OFF);
  int2*   t2s   = (int2*)(ws + T2S_OFF);
  float2* t2w   = (float2*)(ws + T2W_OFF);
  float*  oe    = (float*)(ws + OE_OFF);
  float*  hgate = (float*)(ws + OE_OFF);    // fp32 gate hidden aliases OE (disjoint lifetimes)
  u16*    hbuf  = (u16*)(ws + HBUF_OFF);
  u16*    xlo   = (u16*)(ws + XLO_OFF);     // aliases hbuf region (dead before ffn1)
  u16*    w1hT  = (u16*)(ws + W1HT_OFF);
  u16*    w1lT  = (u16*)(ws + W1LT_OFF);

  float* out    = (float*)d_out;
  float* scores = out + (size_t)T_TOK * DDIM;
  float* maskp  = scores + (size_t)T_TOK * NEXP;

  k_convert_x2<<<2048, 256, 0, stream>>>(x, xbf, xlo, T_TOK * DDIM / 4);
  k_bias_eff<<<(DDIM + 255) / 256, 256, 0, stream>>>(gw1, gb1, snr, beff);
  k_transpose_w1split<<<dim3(DDIM / 64, DDIM / 64), 256, 0, stream>>>(gw1, w1hT, w1lT);
  k_transpose_bf16<<<dim3(DDIM / 64, HDIM / 64, NEXP), 256, 0, stream>>>(ew1, ew1t, DDIM, HDIM);
  k_transpose_bf16<<<dim3(HDIM / 64, DDIM / 64, NEXP), 256, 0, stream>>>(ew2, ew2t, HDIM, DDIM);
  k_gate_h_mfma<<<dim3(T_TOK / 128, DDIM / 128), 256, 0, stream>>>(xbf, xlo, w1hT, w1lT, beff, hgate);
  k_gate_logits<<<T_TOK / 4, 256, 0, stream>>>(hgate, gw2, gb2, gu, scores, maskp, pick, t2w);
  k_route<<<NEXP, 1024, 0, stream>>>(pick, tokl, cnts, t2si);
  k_scan<<<1, 64, 0, stream>>>(cnts, basep);

  for (int c = 0; c < HDIM / HC; c++) {
    k_ffn1<<<dim3(T_TOK / 128, HC / 128, NEXP), 256, 0, stream>>>(xbf, ew1t, eb1, tokl, cnts, basep, hbuf, c * HC);
    k_ffn2<<<dim3(T_TOK / 128, DDIM / 128, NEXP), 256, 0, stream>>>(hbuf, ew2t, eb2, cnts, basep, oe, c * HC);
  }
  k_combine<<<T_TOK / 4, 256, 0, stream>>>(oe, t2s, t2w, basep, out);
}